// Round 1
// baseline (3996.837 us; speedup 1.0000x reference)
//
#include <hip/hip_runtime.h>
#include <math.h>

#define BB   4
#define CC   256
#define NN   8192
#define DA   64
#define RSM  128
#define RGEO 16
#define RTOT 2048

// workspace layout (floats)
#define O_QP   0ull
#define O_KP   4194304ull
#define O_PHI  8388608ull
#define O_V    8912896ull
#define O_KV   17301504ull
#define O_KSUM 19398656ull
#define O_DEN  19406848ull
#define O_BN   19439616ull
#define O_FSA  O_V      // fsa reuses v (v dead after k_kv)
#define O_H    0ull     // h reuses qp+kp (dead after k_fsa/k_denom)

// ---------------------------------------------------------------------------
// Stage 1: q,k,v channel GEMMs + FAVOR+ feature maps + GeoRFF phi
// grid = B * (N/64) = 512 blocks, 256 threads
// ---------------------------------------------------------------------------
__global__ __launch_bounds__(256) void k_stage1(
    const float* __restrict__ x, const float* __restrict__ pos,
    const float* __restrict__ Wq, const float* __restrict__ Wk,
    const float* __restrict__ Wv, const float* __restrict__ Psm,
    const float* __restrict__ Wg1, const float* __restrict__ bg1,
    const float* __restrict__ Wg2, const float* __restrict__ bg2,
    const float* __restrict__ log_tau, const float* __restrict__ omega,
    float* __restrict__ qp, float* __restrict__ kp,
    float* __restrict__ phi, float* __restrict__ v)
{
    __shared__ float xs[CC][64];   // 64 KB
    __shared__ float qs[64][65];   // padded: conflict-free column reads
    __shared__ float Ps[64][64];
    __shared__ float red[5][64];

    const int t  = threadIdx.x;
    const int b  = blockIdx.x >> 7;
    const int n0 = (blockIdx.x & 127) << 6;

    {   // load x tile [256 c][64 n], coalesced over n
        const int nn = t & 63;
        for (int c = t >> 6; c < CC; c += 4)
            xs[c][nn] = x[((size_t)(b * CC + c)) * NN + n0 + nn];
        for (int i = t; i < 64 * 64; i += 256)
            Ps[i >> 6][i & 63] = Psm[i];
    }
    __syncthreads();

    const float scale  = 0.35355339059327373f;   // 64^-0.25
    const float inv128 = 0.08838834764831845f;   // 128^-0.5

    // ---- V pass: v[n][o] = sum_c xs[c][n] * Wv[o][c] ----
    {
        const int nn = t >> 2, ob = (t & 3) << 6;
        float acc[64];
        #pragma unroll
        for (int u = 0; u < 64; ++u) acc[u] = 0.f;
        const float4* Wv4 = (const float4*)Wv;
        for (int c4 = 0; c4 < 64; ++c4) {
            const float x0 = xs[c4 * 4 + 0][nn], x1 = xs[c4 * 4 + 1][nn];
            const float x2 = xs[c4 * 4 + 2][nn], x3 = xs[c4 * 4 + 3][nn];
            #pragma unroll
            for (int u = 0; u < 64; ++u) {
                const float4 w = Wv4[(ob + u) * 64 + c4];
                acc[u] = fmaf(x0, w.x, fmaf(x1, w.y, fmaf(x2, w.z, fmaf(x3, w.w, acc[u]))));
            }
        }
        float* vrow = v + ((size_t)(b * NN) + n0 + nn) * CC + ob;
        #pragma unroll
        for (int u4 = 0; u4 < 16; ++u4) {
            float4 o; o.x = acc[u4*4+0]; o.y = acc[u4*4+1]; o.z = acc[u4*4+2]; o.w = acc[u4*4+3];
            *(float4*)&vrow[u4 * 4] = o;
        }
    }

    // ---- Q then K: channel GEMM -> proj -> FAVOR+ features ----
    for (int qk = 0; qk < 2; ++qk) {
        const float* W = qk ? Wk : Wq;
        float* outp    = qk ? kp : qp;
        const int nn = t >> 2, ob = (t & 3) << 4;
        float acc[16];
        #pragma unroll
        for (int u = 0; u < 16; ++u) acc[u] = 0.f;
        const float4* W4 = (const float4*)W;
        for (int c4 = 0; c4 < 64; ++c4) {
            const float x0 = xs[c4 * 4 + 0][nn], x1 = xs[c4 * 4 + 1][nn];
            const float x2 = xs[c4 * 4 + 2][nn], x3 = xs[c4 * 4 + 3][nn];
            #pragma unroll
            for (int u = 0; u < 16; ++u) {
                const float4 w = W4[(ob + u) * 64 + c4];
                acc[u] = fmaf(x0, w.x, fmaf(x1, w.y, fmaf(x2, w.z, fmaf(x3, w.w, acc[u]))));
            }
        }
        #pragma unroll
        for (int u = 0; u < 16; ++u) qs[nn][ob + u] = acc[u] * scale;
        __syncthreads();

        // proj[n][m] = sum_o qs[n][o] * Ps[o][m]   (m block = ob)
        float pr[16];
        #pragma unroll
        for (int u = 0; u < 16; ++u) pr[u] = 0.f;
        for (int o = 0; o < 64; ++o) {
            const float qv = qs[nn][o];
            #pragma unroll
            for (int u = 0; u < 16; ++u)
                pr[u] = fmaf(qv, Ps[o][ob + u], pr[u]);
        }
        float mx = 0.f;
        #pragma unroll
        for (int u = 0; u < 16; ++u) mx = fmaxf(mx, fabsf(pr[u]));
        red[t & 3][nn] = mx;
        __syncthreads();
        if (t < 64)
            red[4][t] = fmaxf(fmaxf(red[0][t], red[1][t]), fmaxf(red[2][t], red[3][t]));
        __syncthreads();
        const float A = red[4][nn];

        float* orow = outp + ((size_t)(b * NN) + n0 + nn) * RSM;
        #pragma unroll
        for (int u4 = 0; u4 < 4; ++u4) {
            float4 e0, e1;
            e0.x = __expf(pr[u4*4+0] - A) * inv128 + 1e-6f;
            e0.y = __expf(pr[u4*4+1] - A) * inv128 + 1e-6f;
            e0.z = __expf(pr[u4*4+2] - A) * inv128 + 1e-6f;
            e0.w = __expf(pr[u4*4+3] - A) * inv128 + 1e-6f;
            e1.x = __expf(-pr[u4*4+0] - A) * inv128 + 1e-6f;
            e1.y = __expf(-pr[u4*4+1] - A) * inv128 + 1e-6f;
            e1.z = __expf(-pr[u4*4+2] - A) * inv128 + 1e-6f;
            e1.w = __expf(-pr[u4*4+3] - A) * inv128 + 1e-6f;
            *(float4*)&orow[ob + u4 * 4]      = e0;
            *(float4*)&orow[64 + ob + u4 * 4] = e1;
        }
        __syncthreads();
    }

    // ---- GeoRFF phi (one n per thread, t<64) ----
    if (t < 64) {
        const int n = t;
        const float* pp = pos + ((size_t)(b * NN) + n0 + n) * 3;
        const float p0 = pp[0], p1 = pp[1], p2 = pp[2];
        float hbuf[16];
        #pragma unroll
        for (int i = 0; i < 16; ++i)
            hbuf[i] = fmaxf(0.f, fmaf(Wg1[i*3+0], p0, fmaf(Wg1[i*3+1], p1, fmaf(Wg1[i*3+2], p2, bg1[i]))));
        const float tau = log1pf(__expf(log_tau[0])) + 1e-6f;
        const float sc  = sqrtf(2.f * tau);
        float z[16]; float zn = 0.f;
        #pragma unroll
        for (int i = 0; i < 16; ++i) {
            float g = bg2[i];
            #pragma unroll
            for (int j = 0; j < 16; ++j) g = fmaf(Wg2[i*16+j], hbuf[j], g);
            z[i] = sc * g;
            zn = fmaf(z[i], z[i], zn);
        }
        zn *= 0.5f;
        float* prow = phi + ((size_t)(b * NN) + n0 + n) * RGEO;
        #pragma unroll
        for (int m4 = 0; m4 < 4; ++m4) {
            float vals[4];
            #pragma unroll
            for (int mm = 0; mm < 4; ++mm) {
                const int m = m4 * 4 + mm;
                float s = 0.f;
                #pragma unroll
                for (int i = 0; i < 16; ++i) s = fmaf(z[i], omega[i*16+m], s);
                vals[mm] = __expf(s - zn) * 0.25f;
            }
            float4 o; o.x = vals[0]; o.y = vals[1]; o.z = vals[2]; o.w = vals[3];
            *(float4*)&prow[m4 * 4] = o;
        }
    }
}

// ---------------------------------------------------------------------------
// kv[r][c] = sum_n (kp[n][i]*phi[n][j]) * v[n][c];  ksum[r] = sum_n kp*phi
// grid = B*32rt*4ct = 512 blocks, 256 threads, 64x64 tile, K=N
// ---------------------------------------------------------------------------
__global__ __launch_bounds__(256) void k_kv(
    const float* __restrict__ kp, const float* __restrict__ phi,
    const float* __restrict__ v, float* __restrict__ kv, float* __restrict__ ksum)
{
    __shared__ float kp_s[64][4];
    __shared__ float ph_s[64][16];
    __shared__ float v_s[64][68];

    const int t  = threadIdx.x;
    const int ct = blockIdx.x & 3;
    const int rt = (blockIdx.x >> 2) & 31;
    const int b  = blockIdx.x >> 7;
    const int tr = t >> 4, tc = t & 15;
    const int il = tr >> 2, j0 = (tr & 3) << 2;
    const int ldn = t >> 2, ld4 = t & 3;
    const bool doSum = (ct == 0);

    float acc[4][4] = {};
    float asum[4] = {0.f, 0.f, 0.f, 0.f};

    for (int nn0 = 0; nn0 < NN; nn0 += 64) {
        if (t < 64)
            *(float4*)kp_s[t] = *(const float4*)&kp[((size_t)(b * NN) + nn0 + t) * RSM + rt * 4];
        *(float4*)&ph_s[ldn][ld4 * 4] = *(const float4*)&phi[((size_t)(b * NN) + nn0 + ldn) * RGEO + ld4 * 4];
        {
            const float* vp = v + ((size_t)(b * NN) + nn0 + ldn) * CC + ct * 64 + ld4 * 16;
            *(float4*)&v_s[ldn][ld4*16 + 0]  = *(const float4*)&vp[0];
            *(float4*)&v_s[ldn][ld4*16 + 4]  = *(const float4*)&vp[4];
            *(float4*)&v_s[ldn][ld4*16 + 8]  = *(const float4*)&vp[8];
            *(float4*)&v_s[ldn][ld4*16 + 12] = *(const float4*)&vp[12];
        }
        __syncthreads();
        #pragma unroll 4
        for (int n = 0; n < 64; ++n) {
            const float kpv = kp_s[n][il];
            const float a0 = kpv * ph_s[n][j0 + 0];
            const float a1 = kpv * ph_s[n][j0 + 1];
            const float a2 = kpv * ph_s[n][j0 + 2];
            const float a3 = kpv * ph_s[n][j0 + 3];
            const float4 b4 = *(const float4*)&v_s[n][tc * 4];
            acc[0][0] = fmaf(a0, b4.x, acc[0][0]); acc[0][1] = fmaf(a0, b4.y, acc[0][1]);
            acc[0][2] = fmaf(a0, b4.z, acc[0][2]); acc[0][3] = fmaf(a0, b4.w, acc[0][3]);
            acc[1][0] = fmaf(a1, b4.x, acc[1][0]); acc[1][1] = fmaf(a1, b4.y, acc[1][1]);
            acc[1][2] = fmaf(a1, b4.z, acc[1][2]); acc[1][3] = fmaf(a1, b4.w, acc[1][3]);
            acc[2][0] = fmaf(a2, b4.x, acc[2][0]); acc[2][1] = fmaf(a2, b4.y, acc[2][1]);
            acc[2][2] = fmaf(a2, b4.z, acc[2][2]); acc[2][3] = fmaf(a2, b4.w, acc[2][3]);
            acc[3][0] = fmaf(a3, b4.x, acc[3][0]); acc[3][1] = fmaf(a3, b4.y, acc[3][1]);
            acc[3][2] = fmaf(a3, b4.z, acc[3][2]); acc[3][3] = fmaf(a3, b4.w, acc[3][3]);
            if (doSum) { asum[0] += a0; asum[1] += a1; asum[2] += a2; asum[3] += a3; }
        }
        __syncthreads();
    }
    #pragma unroll
    for (int rr = 0; rr < 4; ++rr) {
        float4 o; o.x = acc[rr][0]; o.y = acc[rr][1]; o.z = acc[rr][2]; o.w = acc[rr][3];
        *(float4*)&kv[((size_t)(b * RTOT) + rt * 64 + tr * 4 + rr) * CC + ct * 64 + tc * 4] = o;
    }
    if (doSum && tc == 0) {
        #pragma unroll
        for (int rr = 0; rr < 4; ++rr)
            ksum[b * RTOT + rt * 64 + tr * 4 + rr] = asum[rr];
    }
}

// ---------------------------------------------------------------------------
// denom[n] = sum_r qp[n][i]*phi[n][j]*ksum[r] + eps;  grid = B*32, 256 thr
// ---------------------------------------------------------------------------
__global__ __launch_bounds__(256) void k_denom(
    const float* __restrict__ qp, const float* __restrict__ phi,
    const float* __restrict__ ksum, float* __restrict__ den)
{
    __shared__ float ks[RTOT];
    const int t = threadIdx.x;
    const int b = blockIdx.x >> 5;
    const int n = ((blockIdx.x & 31) << 8) + t;
    for (int i = t; i < RTOT; i += 256) ks[i] = ksum[b * RTOT + i];
    __syncthreads();
    float ph[16];
    {
        const float4* p4 = (const float4*)(phi + ((size_t)(b * NN) + n) * RGEO);
        const float4 a = p4[0], bq = p4[1], c = p4[2], d = p4[3];
        ph[0]=a.x; ph[1]=a.y; ph[2]=a.z; ph[3]=a.w;
        ph[4]=bq.x; ph[5]=bq.y; ph[6]=bq.z; ph[7]=bq.w;
        ph[8]=c.x; ph[9]=c.y; ph[10]=c.z; ph[11]=c.w;
        ph[12]=d.x; ph[13]=d.y; ph[14]=d.z; ph[15]=d.w;
    }
    const float4* q4 = (const float4*)(qp + ((size_t)(b * NN) + n) * RSM);
    float acc = 0.f;
    for (int i4 = 0; i4 < 32; ++i4) {
        const float4 q = q4[i4];
        const float qv[4] = {q.x, q.y, q.z, q.w};
        #pragma unroll
        for (int ii = 0; ii < 4; ++ii) {
            const float* kk = &ks[(i4 * 4 + ii) * 16];
            float s = 0.f;
            #pragma unroll
            for (int j = 0; j < 16; ++j) s = fmaf(ph[j], kk[j], s);
            acc = fmaf(qv[ii], s, acc);
        }
    }
    den[b * NN + n] = acc + 1e-6f;
}

// ---------------------------------------------------------------------------
// fsa[n][c] = (sum_r qp[n][i]*phi[n][j]*kv[r][c]) / den[n]
// grid = B*128nt*4ct = 2048 blocks, 256 threads, K=RTOT
// ---------------------------------------------------------------------------
__global__ __launch_bounds__(256) void k_fsa(
    const float* __restrict__ qp, const float* __restrict__ phi,
    const float* __restrict__ kv, const float* __restrict__ den,
    float* __restrict__ fsa)
{
    __shared__ float qp_s[64][4];
    __shared__ float ph_s[64][16];
    __shared__ float kv_s[64][68];
    __shared__ float dn_s[64];

    const int t  = threadIdx.x;
    const int ct = blockIdx.x & 3;
    const int nt = (blockIdx.x >> 2) & 127;
    const int b  = blockIdx.x >> 9;
    const int n0 = nt << 6;
    const int tr = t >> 4, tc = t & 15;
    const int ldn = t >> 2, ld4 = t & 3;

    *(float4*)&ph_s[ldn][ld4 * 4] = *(const float4*)&phi[((size_t)(b * NN) + n0 + ldn) * RGEO + ld4 * 4];
    if (t < 64) dn_s[t] = den[b * NN + n0 + t];

    float acc[4][4] = {};
    for (int ch = 0; ch < 32; ++ch) {
        if (t < 64)
            *(float4*)qp_s[t] = *(const float4*)&qp[((size_t)(b * NN) + n0 + t) * RSM + ch * 4];
        {
            const float* kvp = kv + ((size_t)(b * RTOT) + ch * 64 + ldn) * CC + ct * 64 + ld4 * 16;
            *(float4*)&kv_s[ldn][ld4*16 + 0]  = *(const float4*)&kvp[0];
            *(float4*)&kv_s[ldn][ld4*16 + 4]  = *(const float4*)&kvp[4];
            *(float4*)&kv_s[ldn][ld4*16 + 8]  = *(const float4*)&kvp[8];
            *(float4*)&kv_s[ldn][ld4*16 + 12] = *(const float4*)&kvp[12];
        }
        __syncthreads();
        #pragma unroll 2
        for (int r = 0; r < 64; ++r) {
            const int ril = r >> 4, rj = r & 15;
            const float4 b4 = *(const float4*)&kv_s[r][tc * 4];
            #pragma unroll
            for (int nn = 0; nn < 4; ++nn) {
                const float a = qp_s[tr * 4 + nn][ril] * ph_s[tr * 4 + nn][rj];
                acc[nn][0] = fmaf(a, b4.x, acc[nn][0]);
                acc[nn][1] = fmaf(a, b4.y, acc[nn][1]);
                acc[nn][2] = fmaf(a, b4.z, acc[nn][2]);
                acc[nn][3] = fmaf(a, b4.w, acc[nn][3]);
            }
        }
        __syncthreads();
    }
    #pragma unroll
    for (int nn = 0; nn < 4; ++nn) {
        const float rd = 1.f / dn_s[tr * 4 + nn];
        float4 o; o.x = acc[nn][0]*rd; o.y = acc[nn][1]*rd; o.z = acc[nn][2]*rd; o.w = acc[nn][3]*rd;
        *(float4*)&fsa[((size_t)(b * NN) + n0 + tr * 4 + nn) * CC + ct * 64 + tc * 4] = o;
    }
}

// ---------------------------------------------------------------------------
// h[o][n] = sum_c Wp[o][c]*(x[c][n]-fsa[n][c]);  + BN partial sums (atomics)
// grid = B*(N/64) = 512 blocks, 256 threads
// ---------------------------------------------------------------------------
__global__ __launch_bounds__(256) void k_h(
    const float* __restrict__ x, const float* __restrict__ fsa,
    const float* __restrict__ Wp, float* __restrict__ h, float* __restrict__ bn)
{
    __shared__ float ys[CC][65];
    const int t  = threadIdx.x;
    const int b  = blockIdx.x >> 7;
    const int n0 = (blockIdx.x & 127) << 6;
    const int nn = t & 63;

    for (int c = t >> 6; c < CC; c += 4)
        ys[c][nn] = x[((size_t)(b * CC) + c) * NN + n0 + nn];
    __syncthreads();
    for (int k = 0; k < 64; ++k) {
        const int e = t + 256 * k;
        const int n2 = e >> 8, c2 = e & 255;
        ys[c2][n2] -= fsa[((size_t)(b * NN) + n0 + n2) * CC + c2];
    }
    __syncthreads();
    {
        const int n2 = t >> 2, ob = (t & 3) << 6;
        float acc[64];
        #pragma unroll
        for (int u = 0; u < 64; ++u) acc[u] = 0.f;
        const float4* Wp4 = (const float4*)Wp;
        for (int c4 = 0; c4 < 64; ++c4) {
            const float y0 = ys[c4*4+0][n2], y1 = ys[c4*4+1][n2];
            const float y2 = ys[c4*4+2][n2], y3 = ys[c4*4+3][n2];
            #pragma unroll
            for (int u = 0; u < 64; ++u) {
                const float4 w = Wp4[(ob + u) * 64 + c4];
                acc[u] = fmaf(y0, w.x, fmaf(y1, w.y, fmaf(y2, w.z, fmaf(y3, w.w, acc[u]))));
            }
        }
        __syncthreads();
        #pragma unroll
        for (int u = 0; u < 64; ++u) ys[ob + u][n2] = acc[u];
    }
    __syncthreads();
    {
        float s = 0.f, s2 = 0.f;
        #pragma unroll 8
        for (int k = 0; k < 64; ++k) { const float hv = ys[t][k]; s += hv; s2 = fmaf(hv, hv, s2); }
        atomicAdd(&bn[t], s);
        atomicAdd(&bn[256 + t], s2);
    }
    for (int c = t >> 6; c < CC; c += 4)
        h[((size_t)(b * CC) + c) * NN + n0 + nn] = ys[c][nn];
}

__global__ void k_zero(float* __restrict__ bn)
{
    const int t = threadIdx.x;
    bn[t] = 0.f;
    bn[256 + t] = 0.f;
}

__global__ void k_bnfin(float* __restrict__ bn, const float* __restrict__ gamma,
                        const float* __restrict__ beta)
{
    const int c = threadIdx.x;
    const float invn = 1.f / 32768.f;
    const float mean = bn[c] * invn;
    const float var  = bn[256 + c] * invn - mean * mean;
    const float s    = gamma[c] * rsqrtf(var + 1e-5f);
    bn[512 + c] = s;
    bn[768 + c] = fmaf(-mean, s, beta[c]);
}

__global__ __launch_bounds__(256) void k_apply(
    const float* __restrict__ h, const float* __restrict__ x,
    const float* __restrict__ bn, float* __restrict__ out)
{
    const int total4 = BB * CC * NN / 4;
    for (int i = blockIdx.x * 256 + threadIdx.x; i < total4; i += 2048 * 256) {
        const int ch = (i >> 11) & 255;   // N/4 = 2048 float4 per (b,c) row
        const float s = bn[512 + ch], bb = bn[768 + ch];
        const float4 hv = ((const float4*)h)[i];
        const float4 xv = ((const float4*)x)[i];
        float4 o;
        o.x = fmaxf(fmaf(hv.x, s, bb), 0.f) + xv.x;
        o.y = fmaxf(fmaf(hv.y, s, bb), 0.f) + xv.y;
        o.z = fmaxf(fmaf(hv.z, s, bb), 0.f) + xv.z;
        o.w = fmaxf(fmaf(hv.w, s, bb), 0.f) + xv.w;
        ((float4*)out)[i] = o;
    }
}

extern "C" void kernel_launch(void* const* d_in, const int* in_sizes, int n_in,
                              void* d_out, int out_size, void* d_ws, size_t ws_size,
                              hipStream_t stream)
{
    (void)in_sizes; (void)n_in; (void)out_size; (void)ws_size;
    const float* x       = (const float*)d_in[0];
    const float* pos     = (const float*)d_in[1];
    const float* Wq      = (const float*)d_in[2];
    const float* Wk      = (const float*)d_in[3];
    const float* Wv      = (const float*)d_in[4];
    const float* Psm     = (const float*)d_in[5];
    const float* Wg1     = (const float*)d_in[6];
    const float* bg1     = (const float*)d_in[7];
    const float* Wg2     = (const float*)d_in[8];
    const float* bg2     = (const float*)d_in[9];
    const float* log_tau = (const float*)d_in[10];
    const float* omega   = (const float*)d_in[11];
    const float* Wp      = (const float*)d_in[12];
    const float* gamma   = (const float*)d_in[13];
    const float* beta    = (const float*)d_in[14];
    float* w   = (float*)d_ws;
    float* out = (float*)d_out;

    float* qp   = w + O_QP;
    float* kp   = w + O_KP;
    float* phi  = w + O_PHI;
    float* v    = w + O_V;
    float* kv   = w + O_KV;
    float* ksum = w + O_KSUM;
    float* den  = w + O_DEN;
    float* bn   = w + O_BN;
    float* fsa  = w + O_FSA;
    float* h    = w + O_H;

    k_zero<<<1, 256, 0, stream>>>(bn);
    k_stage1<<<512, 256, 0, stream>>>(x, pos, Wq, Wk, Wv, Psm, Wg1, bg1, Wg2, bg2,
                                      log_tau, omega, qp, kp, phi, v);
    k_kv<<<512, 256, 0, stream>>>(kp, phi, v, kv, ksum);
    k_denom<<<128, 256, 0, stream>>>(qp, phi, ksum, den);
    k_fsa<<<2048, 256, 0, stream>>>(qp, phi, kv, den, fsa);
    k_h<<<512, 256, 0, stream>>>(x, fsa, Wp, h, bn);
    k_bnfin<<<1, 256, 0, stream>>>(bn, gamma, beta);
    k_apply<<<2048, 256, 0, stream>>>(h, x, bn, out);
}

// Round 2
// 407.718 us; speedup vs baseline: 9.8029x; 9.8029x over previous
//
#include <hip/hip_runtime.h>
#include <hip/hip_bf16.h>
#include <math.h>

#define BB 4
#define CC 256
#define NN 8192
#define RSM 128
#define RGEO 16

typedef __attribute__((ext_vector_type(8))) short short8v;
typedef __attribute__((ext_vector_type(4))) float f32x4;
typedef __attribute__((ext_vector_type(4))) unsigned int u32x4;

#define MFMA16 __builtin_amdgcn_mfma_f32_16x16x32_bf16

// ---- workspace byte offsets (total 62,337,024 B; proven-safe budget ~74 MB) ----
#define P_QP   0ull          // qp  [B][N][128] bf16   (8 MB)   -- h overlays later
#define P_KPT  8388608ull    // kp_t[B][128][N] bf16   (8 MB)
#define P_PHIR 16777216ull   // phi_row [B][N][16] bf16 (1 MB)
#define P_PHIT 17825792ull   // phi_t [B][16][N] bf16   (1 MB)
#define P_XT   18874368ull   // x^T bf16 [B][N][256]   (16 MB)
#define P_VT   35651584ull   // v_t [B][320][N] bf16   (20.97 MB)
#define P_YNT  35651584ull   // y_nt [B][N][256] bf16  (16 MB, overlays v_t after k_kv)
#define P_KVT  56623104ull   // kv_t [B][320][2048] bf16 (5.24 MB; row 256 = ksum)
#define P_DEN  61865984ull   // den [B][N] f32 (128 KB)
#define P_WQK  61997056ull   // Wqk bf16 [128][256]
#define P_WV   62062592ull   // Wv  bf16 [256][256]
#define P_WP   62193664ull   // Wp  bf16 [256][256]
#define P_PSMT 62324736ull   // Psm^T*scale bf16 [64][64]
#define P_BN   62332928ull   // bn f32 [1024] (512:scale 768:bias)
#define P_H    0ull          // h bf16 [B][256][N] (16 MB, overlays qp+kp_t after k_fsa)

__device__ __forceinline__ unsigned short f2bu(float f){
    __hip_bfloat16 h = __float2bfloat16(f);
    return __builtin_bit_cast(unsigned short, h);
}
__device__ __forceinline__ float bu2f(unsigned short u){
    return __builtin_bit_cast(float, ((unsigned int)u) << 16);
}
__device__ __forceinline__ unsigned int pack2(float a, float b){
    return (unsigned int)f2bu(a) | (((unsigned int)f2bu(b)) << 16);
}
__device__ __forceinline__ int swz128(int row, int cb){ return (row*128 + cb) ^ ((row & 7) << 4); }
__device__ __forceinline__ int swz256(int row, int cb){ return (row*256 + cb) ^ ((row & 7) << 4); }

// stage a 64-row x 64-elem bf16 tile (rowStride in elems) into swizzled LDS (128B rows)
__device__ __forceinline__ void stage64(const unsigned short* __restrict__ g, size_t stride,
                                        char* lds, int t){
    #pragma unroll
    for (int i = 0; i < 2; ++i){
        int id = t + 256*i; int row = id >> 3, q = id & 7;
        short8v v = *(const short8v*)(g + (size_t)row*stride + q*8);
        *(short8v*)(lds + swz128(row, q*16)) = v;
    }
}
__device__ __forceinline__ short8v fld(const char* lds, int row, int cb){
    return *(const short8v*)(lds + swz128(row, cb));
}
// 64x64x64 block step: 4 waves as 2x2, each wave 32x32 (2x2 frags)
__device__ __forceinline__ void mfma8(const char* As, const char* Bs, f32x4 acc[2][2],
                                      int wm, int wn, int lr, int lq){
    #pragma unroll
    for (int kk = 0; kk < 2; ++kk){
        short8v a0 = fld(As, wm*32 + lr,      kk*64 + lq*16);
        short8v a1 = fld(As, wm*32 + 16 + lr, kk*64 + lq*16);
        short8v b0 = fld(Bs, wn*32 + lr,      kk*64 + lq*16);
        short8v b1 = fld(Bs, wn*32 + 16 + lr, kk*64 + lq*16);
        acc[0][0] = MFMA16(a0, b0, acc[0][0], 0, 0, 0);
        acc[0][1] = MFMA16(a0, b1, acc[0][1], 0, 0, 0);
        acc[1][0] = MFMA16(a1, b0, acc[1][0], 0, 0, 0);
        acc[1][1] = MFMA16(a1, b1, acc[1][1], 0, 0, 0);
    }
}

// ---------------------------------------------------------------------------
// prep: bf16 weight conversion + v_t pad rows (256=ones, 257..319=0)
// ---------------------------------------------------------------------------
__global__ __launch_bounds__(256) void k_prep(const float* __restrict__ Wq, const float* __restrict__ Wk,
    const float* __restrict__ Wv, const float* __restrict__ Wp, const float* __restrict__ Psm,
    unsigned short* __restrict__ Wqk_bf, unsigned short* __restrict__ Wv_bf,
    unsigned short* __restrict__ Wp_bf, unsigned short* __restrict__ Psm_t,
    unsigned short* __restrict__ v_t)
{
    const int tid = blockIdx.x*256 + threadIdx.x;
    const int nth = 64*256;
    for (int i = tid; i < 32768; i += nth){
        int o = i >> 8, c = i & 255;
        Wqk_bf[i] = f2bu(o < 64 ? Wq[o*256 + c] : Wk[(o-64)*256 + c]);
    }
    for (int i = tid; i < 65536; i += nth) Wv_bf[i] = f2bu(Wv[i]);
    for (int i = tid; i < 65536; i += nth) Wp_bf[i] = f2bu(Wp[i]);
    for (int i = tid; i < 4096; i += nth){
        int m = i >> 6, o = i & 63;
        Psm_t[i] = f2bu(Psm[o*64 + m] * 0.35355339059327373f);
    }
    for (int i = tid; i < BB*64*NN; i += nth){
        int b = i >> 19, rem = i & 524287;
        int row = rem >> 13, n = rem & 8191;
        v_t[((size_t)(b*320 + 256 + row))*NN + n] = (row == 0) ? (unsigned short)0x3F80 : (unsigned short)0;
    }
}

// ---------------------------------------------------------------------------
// x [B][C][N] f32 -> x^T [B][N][C] bf16
// ---------------------------------------------------------------------------
__global__ __launch_bounds__(256) void k_xt(const float* __restrict__ x, unsigned short* __restrict__ xT)
{
    __shared__ float xs[64][65];
    const int t = threadIdx.x;
    const int b  = blockIdx.x >> 9;
    const int ct = (blockIdx.x >> 7) & 3;
    const int nt = blockIdx.x & 127;
    const int c0 = ct*64, n0 = nt*64;
    #pragma unroll
    for (int i = 0; i < 4; ++i){
        int id = t + 256*i; int row = id >> 4, fq = id & 15;
        f32x4 v = *(const f32x4*)(x + ((size_t)(b*CC + c0 + row))*NN + n0 + fq*4);
        xs[row][fq*4+0] = v[0]; xs[row][fq*4+1] = v[1];
        xs[row][fq*4+2] = v[2]; xs[row][fq*4+3] = v[3];
    }
    __syncthreads();
    #pragma unroll
    for (int i = 0; i < 2; ++i){
        int id = t + 256*i; int n = id >> 3, q = id & 7;
        u32x4 o;
        #pragma unroll
        for (int j2 = 0; j2 < 4; ++j2)
            o[j2] = pack2(xs[q*8 + j2*2][n], xs[q*8 + j2*2+1][n]);
        *(u32x4*)(void*)(xT + ((size_t)(b*NN + n0 + n))*CC + c0 + q*8) = o;
    }
}

// ---------------------------------------------------------------------------
// weight GEMM: out[b][c][n] = sum_k A[c][k] * B[b][n][k]   (used for v and h)
// grid = 4 * 4ct * 128nt = 2048
// ---------------------------------------------------------------------------
__global__ __launch_bounds__(256) void k_wgemm(const unsigned short* __restrict__ A,
    const unsigned short* __restrict__ Bsrc, unsigned short* __restrict__ out, int orows)
{
    __shared__ __align__(16) char As[8192];
    __shared__ __align__(16) char Bs[8192];
    const int t = threadIdx.x;
    const int l = t & 63, w = t >> 6, wm = w >> 1, wn = w & 1, lr = l & 15, lq = l >> 4;
    const int b  = blockIdx.x >> 9;
    const int ct = (blockIdx.x >> 7) & 3;
    const int nt = blockIdx.x & 127;
    const int c0 = ct*64, n0 = nt*64;

    f32x4 acc[2][2] = {};
    for (int ks = 0; ks < 4; ++ks){
        stage64(A + (size_t)c0*256 + ks*64, 256, As, t);
        stage64(Bsrc + ((size_t)(b*NN + n0))*256 + ks*64, 256, Bs, t);
        __syncthreads();
        mfma8(As, Bs, acc, wm, wn, lr, lq);
        __syncthreads();
    }
    #pragma unroll
    for (int mi = 0; mi < 2; ++mi)
        #pragma unroll
        for (int ni = 0; ni < 2; ++ni)
            #pragma unroll
            for (int r = 0; r < 4; ++r){
                int c = c0 + wm*32 + mi*16 + lq*4 + r;
                int n = n0 + wn*32 + ni*16 + lr;
                out[((size_t)(b*orows + c))*NN + n] = f2bu(acc[mi][ni][r]);
            }
}

// ---------------------------------------------------------------------------
// qk: t = Wqk*x (128xN), proj = Psm_t * t (2x 64xN), FAVOR+ features
// grid = 4 * 128nt = 512
// ---------------------------------------------------------------------------
__global__ __launch_bounds__(256) void k_qk(const unsigned short* __restrict__ Wqk,
    const unsigned short* __restrict__ xT, const unsigned short* __restrict__ Psm_t,
    unsigned short* __restrict__ qp, unsigned short* __restrict__ kp_t)
{
    __shared__ __align__(16) char As[16384];
    __shared__ __align__(16) char Bs[8192];
    __shared__ __align__(16) char Ts[16384];
    __shared__ __align__(16) char Ps[8192];
    const int t = threadIdx.x;
    const int l = t & 63, w = t >> 6, wm = w >> 1, wn = w & 1, lr = l & 15, lq = l >> 4;
    const int b  = blockIdx.x >> 7;
    const int nt = blockIdx.x & 127;
    const int n0 = nt*64;

    stage64(Psm_t, 64, Ps, t);

    f32x4 acc[4][2] = {};
    for (int ks = 0; ks < 4; ++ks){
        #pragma unroll
        for (int i = 0; i < 4; ++i){
            int id = t + 256*i; int row = id >> 3, q = id & 7;
            short8v v = *(const short8v*)(Wqk + (size_t)row*256 + ks*64 + q*8);
            *(short8v*)(As + swz128(row, q*16)) = v;
        }
        stage64(xT + ((size_t)(b*NN + n0))*256 + ks*64, 256, Bs, t);
        __syncthreads();
        #pragma unroll
        for (int kk = 0; kk < 2; ++kk){
            short8v b0 = fld(Bs, wn*32 + lr,      kk*64 + lq*16);
            short8v b1 = fld(Bs, wn*32 + 16 + lr, kk*64 + lq*16);
            #pragma unroll
            for (int mi = 0; mi < 4; ++mi){
                short8v a = fld(As, wm*64 + mi*16 + lr, kk*64 + lq*16);
                acc[mi][0] = MFMA16(a, b0, acc[mi][0], 0, 0, 0);
                acc[mi][1] = MFMA16(a, b1, acc[mi][1], 0, 0, 0);
            }
        }
        __syncthreads();
    }
    // t -> Ts [n][128] bf16 (256B rows, swizzled)
    #pragma unroll
    for (int mi = 0; mi < 4; ++mi)
        #pragma unroll
        for (int ni = 0; ni < 2; ++ni){
            int op = (wm*64 + mi*16 + lq*4)*2;
            int nrow = wn*32 + ni*16 + lr;
            *(unsigned int*)(Ts + swz256(nrow, op))     = pack2(acc[mi][ni][0], acc[mi][ni][1]);
            *(unsigned int*)(Ts + swz256(nrow, op + 4)) = pack2(acc[mi][ni][2], acc[mi][ni][3]);
        }
    __syncthreads();

    const float inv128 = 0.08838834764831845f;
    for (int p = 0; p < 2; ++p){
        f32x4 ac[4] = {};
        #pragma unroll
        for (int kk = 0; kk < 2; ++kk){
            short8v bf = *(const short8v*)(Ts + swz256(w*16 + lr, p*128 + kk*64 + lq*16));
            #pragma unroll
            for (int mi = 0; mi < 4; ++mi){
                short8v a = *(const short8v*)(Ps + swz128(mi*16 + lr, kk*64 + lq*16));
                ac[mi] = MFMA16(a, bf, ac[mi], 0, 0, 0);
            }
        }
        float mx = 0.f;
        #pragma unroll
        for (int mi = 0; mi < 4; ++mi)
            #pragma unroll
            for (int r = 0; r < 4; ++r) mx = fmaxf(mx, fabsf(ac[mi][r]));
        mx = fmaxf(mx, __shfl_xor(mx, 16));
        mx = fmaxf(mx, __shfl_xor(mx, 32));
        const int n = n0 + w*16 + lr;
        if (p == 0){
            unsigned short* qr = qp + ((size_t)(b*NN + n))*RSM;
            #pragma unroll
            for (int mi = 0; mi < 4; ++mi){
                float e0 = __expf( ac[mi][0]-mx)*inv128 + 1e-6f;
                float e1 = __expf( ac[mi][1]-mx)*inv128 + 1e-6f;
                float e2 = __expf( ac[mi][2]-mx)*inv128 + 1e-6f;
                float e3 = __expf( ac[mi][3]-mx)*inv128 + 1e-6f;
                float g0 = __expf(-ac[mi][0]-mx)*inv128 + 1e-6f;
                float g1 = __expf(-ac[mi][1]-mx)*inv128 + 1e-6f;
                float g2 = __expf(-ac[mi][2]-mx)*inv128 + 1e-6f;
                float g3 = __expf(-ac[mi][3]-mx)*inv128 + 1e-6f;
                int i0 = mi*16 + lq*4;
                uint2 pu; pu.x = pack2(e0, e1); pu.y = pack2(e2, e3);
                uint2 nu; nu.x = pack2(g0, g1); nu.y = pack2(g2, g3);
                *(uint2*)(void*)(qr + i0)      = pu;
                *(uint2*)(void*)(qr + 64 + i0) = nu;
            }
        } else {
            unsigned short* kb = kp_t + (size_t)(b*RSM)*NN + n;
            #pragma unroll
            for (int mi = 0; mi < 4; ++mi){
                int i0 = mi*16 + lq*4;
                #pragma unroll
                for (int r = 0; r < 4; ++r){
                    kb[(size_t)(i0 + r)*NN]      = f2bu(__expf( ac[mi][r]-mx)*inv128 + 1e-6f);
                    kb[(size_t)(i0 + r + 64)*NN] = f2bu(__expf(-ac[mi][r]-mx)*inv128 + 1e-6f);
                }
            }
        }
    }
}

// ---------------------------------------------------------------------------
// GeoRFF phi -> phi_row [B][N][16] bf16 + phi_t [B][16][N] bf16 ; grid=128
// ---------------------------------------------------------------------------
__global__ __launch_bounds__(256) void k_phi(const float* __restrict__ pos,
    const float* __restrict__ Wg1, const float* __restrict__ bg1,
    const float* __restrict__ Wg2, const float* __restrict__ bg2,
    const float* __restrict__ log_tau, const float* __restrict__ omega,
    unsigned short* __restrict__ phi_row, unsigned short* __restrict__ phi_t)
{
    const int t = threadIdx.x;
    const int b = blockIdx.x >> 5;
    const int n = ((blockIdx.x & 31) << 8) + t;
    const float* pp = pos + ((size_t)(b*NN + n))*3;
    const float p0 = pp[0], p1 = pp[1], p2 = pp[2];
    float hb[16];
    #pragma unroll
    for (int i = 0; i < 16; ++i)
        hb[i] = fmaxf(0.f, fmaf(Wg1[i*3+0], p0, fmaf(Wg1[i*3+1], p1, fmaf(Wg1[i*3+2], p2, bg1[i]))));
    const float tau = log1pf(__expf(log_tau[0])) + 1e-6f;
    const float sc  = sqrtf(2.f*tau);
    float z[16]; float zn = 0.f;
    #pragma unroll
    for (int i = 0; i < 16; ++i){
        float g = bg2[i];
        #pragma unroll
        for (int j = 0; j < 16; ++j) g = fmaf(Wg2[i*16+j], hb[j], g);
        z[i] = sc*g; zn = fmaf(z[i], z[i], zn);
    }
    zn *= 0.5f;
    float val[16];
    #pragma unroll
    for (int m = 0; m < 16; ++m){
        float s = 0.f;
        #pragma unroll
        for (int i = 0; i < 16; ++i) s = fmaf(z[i], omega[i*16+m], s);
        val[m] = __expf(s - zn)*0.25f;
    }
    unsigned short* pr = phi_row + ((size_t)(b*NN + n))*16;
    u32x4 o0, o1;
    #pragma unroll
    for (int j2 = 0; j2 < 4; ++j2){
        o0[j2] = pack2(val[j2*2], val[j2*2+1]);
        o1[j2] = pack2(val[8+j2*2], val[8+j2*2+1]);
    }
    *(u32x4*)(void*)pr = o0;
    *(u32x4*)(void*)(pr + 8) = o1;
    #pragma unroll
    for (int m = 0; m < 16; ++m)
        phi_t[((size_t)(b*RGEO + m))*NN + n] = f2bu(val[m]);
}

// ---------------------------------------------------------------------------
// kv_t[b][c][r] = sum_n v_t[c][n]*Phik[n][r]   (c=256 row gives ksum)
// grid = 4 * 5ct * 32rt = 640
// ---------------------------------------------------------------------------
__global__ __launch_bounds__(256) void k_kv(const unsigned short* __restrict__ kp_t,
    const unsigned short* __restrict__ phi_t, const unsigned short* __restrict__ v_t,
    unsigned short* __restrict__ kv_t)
{
    __shared__ __align__(16) char As[8192];
    __shared__ __align__(16) char Bs[8192];
    const int t = threadIdx.x;
    const int l = t & 63, w = t >> 6, wm = w >> 1, wn = w & 1, lr = l & 15, lq = l >> 4;
    const int b  = blockIdx.x / 160;
    const int rr = blockIdx.x % 160;
    const int ct = rr >> 5, rt = rr & 31;
    const int c0 = ct*64, r0 = rt*64;
    const int rl = t >> 2, u = t & 3;
    const int rg = r0 + rl;
    const unsigned short* kpr = kp_t + ((size_t)(b*RSM  + (rg >> 4)))*NN;
    const unsigned short* phr = phi_t + ((size_t)(b*RGEO + (rg & 15)))*NN;

    f32x4 acc[2][2] = {};
    for (int ks = 0; ks < 128; ++ks){
        const int nk = ks*64;
        stage64(v_t + ((size_t)(b*320 + c0))*NN + nk, NN, As, t);
        {
            const int nb = nk + u*16;
            short8v k0 = *(const short8v*)(kpr + nb);
            short8v k1 = *(const short8v*)(kpr + nb + 8);
            short8v q0 = *(const short8v*)(phr + nb);
            short8v q1 = *(const short8v*)(phr + nb + 8);
            u32x4 o0, o1;
            #pragma unroll
            for (int j2 = 0; j2 < 4; ++j2){
                o0[j2] = pack2(bu2f((unsigned short)k0[j2*2])  *bu2f((unsigned short)q0[j2*2]),
                               bu2f((unsigned short)k0[j2*2+1])*bu2f((unsigned short)q0[j2*2+1]));
                o1[j2] = pack2(bu2f((unsigned short)k1[j2*2])  *bu2f((unsigned short)q1[j2*2]),
                               bu2f((unsigned short)k1[j2*2+1])*bu2f((unsigned short)q1[j2*2+1]));
            }
            *(u32x4*)(Bs + swz128(rl, u*32))      = o0;
            *(u32x4*)(Bs + swz128(rl, u*32 + 16)) = o1;
        }
        __syncthreads();
        mfma8(As, Bs, acc, wm, wn, lr, lq);
        __syncthreads();
    }
    #pragma unroll
    for (int mi = 0; mi < 2; ++mi)
        #pragma unroll
        for (int ni = 0; ni < 2; ++ni)
            #pragma unroll
            for (int r = 0; r < 4; ++r){
                int c = c0 + wm*32 + mi*16 + lq*4 + r;
                int rg2 = r0 + wn*32 + ni*16 + lr;
                kv_t[((size_t)(b*320 + c))*2048 + rg2] = f2bu(acc[mi][ni][r]);
            }
}

// ---------------------------------------------------------------------------
// den[b][n] = sum_r qp[n][i]*phi[n][j]*ksum[r] + eps ; grid=128
// ---------------------------------------------------------------------------
__global__ __launch_bounds__(256) void k_denom(const unsigned short* __restrict__ qp,
    const unsigned short* __restrict__ phi_row, const unsigned short* __restrict__ kv_t,
    float* __restrict__ den)
{
    __shared__ float ks[2048];
    const int t = threadIdx.x;
    const int b = blockIdx.x >> 5;
    const int n = ((blockIdx.x & 31) << 8) + t;
    const unsigned short* ksrc = kv_t + ((size_t)(b*320 + 256))*2048;
    #pragma unroll
    for (int i = 0; i < 8; ++i){ int idx = t + 256*i; ks[idx] = bu2f(ksrc[idx]); }
    __syncthreads();
    float phf[16];
    {
        const unsigned short* pr = phi_row + ((size_t)(b*NN + n))*16;
        short8v a = *(const short8v*)pr;
        short8v c = *(const short8v*)(pr + 8);
        #pragma unroll
        for (int j = 0; j < 8; ++j){ phf[j] = bu2f((unsigned short)a[j]); phf[8+j] = bu2f((unsigned short)c[j]); }
    }
    const unsigned short* qr = qp + ((size_t)(b*NN + n))*RSM;
    float acc = 0.f;
    for (int i = 0; i < 128; i += 8){
        short8v qv = *(const short8v*)(qr + i);
        #pragma unroll
        for (int ii = 0; ii < 8; ++ii){
            const float* kk = &ks[(i + ii)*16];
            float s = 0.f;
            #pragma unroll
            for (int j = 0; j < 16; ++j) s = fmaf(phf[j], kk[j], s);
            acc = fmaf(bu2f((unsigned short)qv[ii]), s, acc);
        }
    }
    den[b*NN + n] = acc + 1e-6f;
}

// ---------------------------------------------------------------------------
// fsa^T[c][n] = sum_r kv_t[c][r]*Phiq[n][r] / den ; writes y_nt[n][c]=x-fsa bf16
// grid = 4 * 4ct * 128nt = 2048
// ---------------------------------------------------------------------------
__global__ __launch_bounds__(256) void k_fsa(const unsigned short* __restrict__ kv_t,
    const unsigned short* __restrict__ qp, const unsigned short* __restrict__ phi_row,
    const float* __restrict__ den, const unsigned short* __restrict__ xT,
    unsigned short* __restrict__ y_nt)
{
    __shared__ __align__(16) char As[8192];
    __shared__ __align__(16) char Bs[8192];
    __shared__ __align__(16) char Ys[8192];
    const int t = threadIdx.x;
    const int l = t & 63, w = t >> 6, wm = w >> 1, wn = w & 1, lr = l & 15, lq = l >> 4;
    const int b  = blockIdx.x >> 9;
    const int ct = (blockIdx.x >> 7) & 3;
    const int nt = blockIdx.x & 127;
    const int c0 = ct*64, n0 = nt*64;
    const int nl = t >> 2, u = t & 3;

    float phf[16];
    {
        const unsigned short* pr = phi_row + ((size_t)(b*NN + n0 + nl))*16;
        short8v a = *(const short8v*)pr;
        short8v c = *(const short8v*)(pr + 8);
        #pragma unroll
        for (int j = 0; j < 8; ++j){ phf[j] = bu2f((unsigned short)a[j]); phf[8+j] = bu2f((unsigned short)c[j]); }
    }
    const unsigned short* qprow = qp + ((size_t)(b*NN + n0 + nl))*RSM;

    f32x4 acc[2][2] = {};
    for (int ks = 0; ks < 32; ++ks){
        stage64(kv_t + ((size_t)(b*320 + c0))*2048 + ks*64, 2048, As, t);
        {
            float qv = bu2f(qprow[ks*4 + u]);
            u32x4 o0, o1;
            #pragma unroll
            for (int j2 = 0; j2 < 4; ++j2){
                o0[j2] = pack2(qv*phf[j2*2],     qv*phf[j2*2+1]);
                o1[j2] = pack2(qv*phf[8+j2*2],   qv*phf[8+j2*2+1]);
            }
            *(u32x4*)(Bs + swz128(nl, u*32))      = o0;
            *(u32x4*)(Bs + swz128(nl, u*32 + 16)) = o1;
        }
        __syncthreads();
        mfma8(As, Bs, acc, wm, wn, lr, lq);
        __syncthreads();
    }
    #pragma unroll
    for (int ni = 0; ni < 2; ++ni){
        float rd = 1.0f / den[(size_t)b*NN + n0 + wn*32 + ni*16 + lr];
        #pragma unroll
        for (int mi = 0; mi < 2; ++mi){
            int cb = (wm*32 + mi*16 + lq*4)*2;
            int nrow = wn*32 + ni*16 + lr;
            *(unsigned int*)(Ys + swz128(nrow, cb))     = pack2(acc[mi][ni][0]*rd, acc[mi][ni][1]*rd);
            *(unsigned int*)(Ys + swz128(nrow, cb + 4)) = pack2(acc[mi][ni][2]*rd, acc[mi][ni][3]*rd);
        }
    }
    __syncthreads();
    #pragma unroll
    for (int i = 0; i < 2; ++i){
        int q = u + i*4;
        short8v fs = *(const short8v*)(Ys + swz128(nl, q*16));
        short8v xv = *(const short8v*)(xT + ((size_t)(b*NN + n0 + nl))*CC + c0 + q*8);
        u32x4 o;
        #pragma unroll
        for (int j2 = 0; j2 < 4; ++j2){
            float y0 = bu2f((unsigned short)xv[j2*2])   - bu2f((unsigned short)fs[j2*2]);
            float y1 = bu2f((unsigned short)xv[j2*2+1]) - bu2f((unsigned short)fs[j2*2+1]);
            o[j2] = pack2(y0, y1);
        }
        *(u32x4*)(void*)(y_nt + ((size_t)(b*NN + n0 + nl))*CC + c0 + q*8) = o;
    }
}

// ---------------------------------------------------------------------------
// BN stats per channel ; grid=256
// ---------------------------------------------------------------------------
__global__ __launch_bounds__(256) void k_bnstat(const unsigned short* __restrict__ h,
    const float* __restrict__ gamma, const float* __restrict__ beta, float* __restrict__ bn)
{
    __shared__ float s1[256], s2[256];
    const int t = threadIdx.x, c = blockIdx.x;
    float a1 = 0.f, a2 = 0.f;
    for (int b = 0; b < 4; ++b){
        const unsigned short* hr = h + ((size_t)(b*CC + c))*NN;
        #pragma unroll
        for (int i = 0; i < 4; ++i){
            short8v v = *(const short8v*)(hr + (t + i*256)*8);
            #pragma unroll
            for (int j = 0; j < 8; ++j){ float f = bu2f((unsigned short)v[j]); a1 += f; a2 = fmaf(f, f, a2); }
        }
    }
    s1[t] = a1; s2[t] = a2; __syncthreads();
    for (int st = 128; st > 0; st >>= 1){
        if (t < st){ s1[t] += s1[t + st]; s2[t] += s2[t + st]; }
        __syncthreads();
    }
    if (t == 0){
        float inv = 1.f/32768.f;
        float mean = s1[0]*inv, var = s2[0]*inv - mean*mean;
        float sc = gamma[c]*rsqrtf(var + 1e-5f);
        bn[512 + c] = sc; bn[768 + c] = fmaf(-mean, sc, beta[c]);
    }
}

// ---------------------------------------------------------------------------
// out = relu(h*s+b) + x ; grid=2048
// ---------------------------------------------------------------------------
__global__ __launch_bounds__(256) void k_apply(const unsigned short* __restrict__ h,
    const float* __restrict__ x, const float* __restrict__ bn, float* __restrict__ out)
{
    const size_t tot8 = (size_t)BB*CC*NN/8;
    for (size_t i = (size_t)blockIdx.x*256 + threadIdx.x; i < tot8; i += 2048*256){
        int c = (int)((i >> 10) & 255);
        float s = bn[512 + c], bb = bn[768 + c];
        short8v hv = *(const short8v*)(h + i*8);
        f32x4 x0 = *(const f32x4*)(x + i*8);
        f32x4 x1 = *(const f32x4*)(x + i*8 + 4);
        f32x4 o0, o1;
        #pragma unroll
        for (int j = 0; j < 4; ++j){
            o0[j] = fmaxf(fmaf(bu2f((unsigned short)hv[j]),     s, bb), 0.f) + x0[j];
            o1[j] = fmaxf(fmaf(bu2f((unsigned short)hv[4 + j]), s, bb), 0.f) + x1[j];
        }
        *(f32x4*)(out + i*8)     = o0;
        *(f32x4*)(out + i*8 + 4) = o1;
    }
}

extern "C" void kernel_launch(void* const* d_in, const int* in_sizes, int n_in,
                              void* d_out, int out_size, void* d_ws, size_t ws_size,
                              hipStream_t stream)
{
    (void)in_sizes; (void)n_in; (void)out_size; (void)ws_size;
    const float* x       = (const float*)d_in[0];
    const float* pos     = (const float*)d_in[1];
    const float* Wq      = (const float*)d_in[2];
    const float* Wk      = (const float*)d_in[3];
    const float* Wv      = (const float*)d_in[4];
    const float* Psm     = (const float*)d_in[5];
    const float* Wg1     = (const float*)d_in[6];
    const float* bg1     = (const float*)d_in[7];
    const float* Wg2     = (const float*)d_in[8];
    const float* bg2     = (const float*)d_in[9];
    const float* log_tau = (const float*)d_in[10];
    const float* omega   = (const float*)d_in[11];
    const float* Wp      = (const float*)d_in[12];
    const float* gamma   = (const float*)d_in[13];
    const float* beta    = (const float*)d_in[14];
    char* W = (char*)d_ws;
    float* out = (float*)d_out;

    unsigned short* qp    = (unsigned short*)(W + P_QP);
    unsigned short* kp_t  = (unsigned short*)(W + P_KPT);
    unsigned short* phir  = (unsigned short*)(W + P_PHIR);
    unsigned short* phit  = (unsigned short*)(W + P_PHIT);
    unsigned short* xT    = (unsigned short*)(W + P_XT);
    unsigned short* v_t   = (unsigned short*)(W + P_VT);
    unsigned short* y_nt  = (unsigned short*)(W + P_YNT);
    unsigned short* kv_t  = (unsigned short*)(W + P_KVT);
    float*          den   = (float*)(W + P_DEN);
    unsigned short* Wqk_b = (unsigned short*)(W + P_WQK);
    unsigned short* Wv_b  = (unsigned short*)(W + P_WV);
    unsigned short* Wp_b  = (unsigned short*)(W + P_WP);
    unsigned short* Psm_t = (unsigned short*)(W + P_PSMT);
    float*          bn    = (float*)(W + P_BN);
    unsigned short* hbuf  = (unsigned short*)(W + P_H);

    k_prep  <<<  64, 256, 0, stream>>>(Wq, Wk, Wv, Wp, Psm, Wqk_b, Wv_b, Wp_b, Psm_t, v_t);
    k_xt    <<<2048, 256, 0, stream>>>(x, xT);
    k_wgemm <<<2048, 256, 0, stream>>>(Wv_b, xT, v_t, 320);
    k_qk    <<< 512, 256, 0, stream>>>(Wqk_b, xT, Psm_t, qp, kp_t);
    k_phi   <<< 128, 256, 0, stream>>>(pos, Wg1, bg1, Wg2, bg2, log_tau, omega, phir, phit);
    k_kv    <<< 640, 256, 0, stream>>>(kp_t, phit, v_t, kv_t);
    k_denom <<< 128, 256, 0, stream>>>(qp, phir, kv_t, den);
    k_fsa   <<<2048, 256, 0, stream>>>(kv_t, qp, phir, den, xT, y_nt);
    k_wgemm <<<2048, 256, 0, stream>>>(Wp_b, y_nt, hbuf, 256);
    k_bnstat<<< 256, 256, 0, stream>>>(hbuf, gamma, beta, bn);
    k_apply <<<2048, 256, 0, stream>>>(hbuf, x, bn, out);
}

// Round 4
// 353.680 us; speedup vs baseline: 11.3007x; 1.1528x over previous
//
#include <hip/hip_runtime.h>
#include <hip/hip_bf16.h>
#include <math.h>

#define BB 4
#define CC 256
#define NN 8192
#define RSM 128
#define RGEO 16

typedef __attribute__((ext_vector_type(8))) short short8v;
typedef __attribute__((ext_vector_type(4))) float f32x4;
typedef __attribute__((ext_vector_type(4))) unsigned int u32x4;

#define MFMA16 __builtin_amdgcn_mfma_f32_16x16x32_bf16

// ---- workspace byte offsets (peak 72.82 MB; ws proven >= 77.76 MB in round 0) ----
#define P_QP   0ull          // qp  [B][N][128] bf16   (8 MB)   -- h overlays later
#define P_KPT  8388608ull    // kp_t[B][128][N] bf16   (8 MB)
#define P_PHIR 16777216ull   // phi_row [B][N][16] bf16 (1 MB)
#define P_PHIT 17825792ull   // phi_t [B][16][N] bf16   (1 MB)
#define P_XT   18874368ull   // x^T bf16 [B][N][256]   (16 MB)
#define P_VT   35651584ull   // v_t [B][320][N] bf16   (20.97 MB)
#define P_YNT  35651584ull   // y_nt [B][N][256] bf16  (16 MB, overlays v_t after k_kv)
#define P_KVT  56623104ull   // kv_t [B][320][2048] bf16 (5.24 MB; row 256 = ksum)
#define P_DEN  61865984ull   // den [B][N] f32 (128 KB)
#define P_WQK  61997056ull   // Wqk bf16 [128][256]
#define P_WV   62062592ull   // Wv  bf16 [256][256]
#define P_WP   62193664ull   // Wp  bf16 [256][256]
#define P_PSMT 62324736ull   // Psm^T*scale bf16 [64][64]
#define P_BN   62332928ull   // bn f32 [1024] (512:scale 768:bias)
#define P_KVF  62337024ull   // kv_f32 [B][320][2048] f32 (10.49 MB) -- K-split accumulator
#define P_H    0ull          // h bf16 [B][256][N] (16 MB, overlays qp+kp_t after k_fsa)

__device__ __forceinline__ unsigned short f2bu(float f){
    __hip_bfloat16 h = __float2bfloat16(f);
    return __builtin_bit_cast(unsigned short, h);
}
__device__ __forceinline__ float bu2f(unsigned short u){
    return __builtin_bit_cast(float, ((unsigned int)u) << 16);
}
__device__ __forceinline__ unsigned int pack2(float a, float b){
    return (unsigned int)f2bu(a) | (((unsigned int)f2bu(b)) << 16);
}
__device__ __forceinline__ int swz128(int row, int cb){ return (row*128 + cb) ^ ((row & 7) << 4); }
__device__ __forceinline__ int swz256(int row, int cb){ return (row*256 + cb) ^ ((row & 7) << 4); }

// stage a 64-row x 64-elem bf16 tile (rowStride in elems) into swizzled LDS (128B rows)
__device__ __forceinline__ void stage64(const unsigned short* __restrict__ g, size_t stride,
                                        char* lds, int t){
    #pragma unroll
    for (int i = 0; i < 2; ++i){
        int id = t + 256*i; int row = id >> 3, q = id & 7;
        short8v v = *(const short8v*)(g + (size_t)row*stride + q*8);
        *(short8v*)(lds + swz128(row, q*16)) = v;
    }
}
__device__ __forceinline__ short8v fld(const char* lds, int row, int cb){
    return *(const short8v*)(lds + swz128(row, cb));
}
// 64x64x64 block step: 4 waves as 2x2, each wave 32x32 (2x2 frags)
__device__ __forceinline__ void mfma8(const char* As, const char* Bs, f32x4 acc[2][2],
                                      int wm, int wn, int lr, int lq){
    #pragma unroll
    for (int kk = 0; kk < 2; ++kk){
        short8v a0 = fld(As, wm*32 + lr,      kk*64 + lq*16);
        short8v a1 = fld(As, wm*32 + 16 + lr, kk*64 + lq*16);
        short8v b0 = fld(Bs, wn*32 + lr,      kk*64 + lq*16);
        short8v b1 = fld(Bs, wn*32 + 16 + lr, kk*64 + lq*16);
        acc[0][0] = MFMA16(a0, b0, acc[0][0], 0, 0, 0);
        acc[0][1] = MFMA16(a0, b1, acc[0][1], 0, 0, 0);
        acc[1][0] = MFMA16(a1, b0, acc[1][0], 0, 0, 0);
        acc[1][1] = MFMA16(a1, b1, acc[1][1], 0, 0, 0);
    }
}

// ---------------------------------------------------------------------------
// prep: bf16 weight conversion + v_t pad rows (256=ones, 257..319=0)
// ---------------------------------------------------------------------------
__global__ __launch_bounds__(256) void k_prep(const float* __restrict__ Wq, const float* __restrict__ Wk,
    const float* __restrict__ Wv, const float* __restrict__ Wp, const float* __restrict__ Psm,
    unsigned short* __restrict__ Wqk_bf, unsigned short* __restrict__ Wv_bf,
    unsigned short* __restrict__ Wp_bf, unsigned short* __restrict__ Psm_t,
    unsigned short* __restrict__ v_t)
{
    const int tid = blockIdx.x*256 + threadIdx.x;
    const int nth = 64*256;
    for (int i = tid; i < 32768; i += nth){
        int o = i >> 8, c = i & 255;
        Wqk_bf[i] = f2bu(o < 64 ? Wq[o*256 + c] : Wk[(o-64)*256 + c]);
    }
    for (int i = tid; i < 65536; i += nth) Wv_bf[i] = f2bu(Wv[i]);
    for (int i = tid; i < 65536; i += nth) Wp_bf[i] = f2bu(Wp[i]);
    for (int i = tid; i < 4096; i += nth){
        int m = i >> 6, o = i & 63;
        Psm_t[i] = f2bu(Psm[o*64 + m] * 0.35355339059327373f);
    }
    for (int i = tid; i < BB*64*NN; i += nth){
        int b = i >> 19, rem = i & 524287;
        int row = rem >> 13, n = rem & 8191;
        v_t[((size_t)(b*320 + 256 + row))*NN + n] = (row == 0) ? (unsigned short)0x3F80 : (unsigned short)0;
    }
}

// ---------------------------------------------------------------------------
// x [B][C][N] f32 -> x^T [B][N][C] bf16
// ---------------------------------------------------------------------------
__global__ __launch_bounds__(256) void k_xt(const float* __restrict__ x, unsigned short* __restrict__ xT)
{
    __shared__ float xs[64][65];
    const int t = threadIdx.x;
    const int b  = blockIdx.x >> 9;
    const int ct = (blockIdx.x >> 7) & 3;
    const int nt = blockIdx.x & 127;
    const int c0 = ct*64, n0 = nt*64;
    #pragma unroll
    for (int i = 0; i < 4; ++i){
        int id = t + 256*i; int row = id >> 4, fq = id & 15;
        f32x4 v = *(const f32x4*)(x + ((size_t)(b*CC + c0 + row))*NN + n0 + fq*4);
        xs[row][fq*4+0] = v[0]; xs[row][fq*4+1] = v[1];
        xs[row][fq*4+2] = v[2]; xs[row][fq*4+3] = v[3];
    }
    __syncthreads();
    #pragma unroll
    for (int i = 0; i < 2; ++i){
        int id = t + 256*i; int n = id >> 3, q = id & 7;
        u32x4 o;
        #pragma unroll
        for (int j2 = 0; j2 < 4; ++j2)
            o[j2] = pack2(xs[q*8 + j2*2][n], xs[q*8 + j2*2+1][n]);
        *(u32x4*)(void*)(xT + ((size_t)(b*NN + n0 + n))*CC + c0 + q*8) = o;
    }
}

// ---------------------------------------------------------------------------
// weight GEMM: out[b][c][n] = sum_k A[c][k] * B[b][n][k]   (used for v and h)
// grid = 4 * 4ct * 128nt = 2048
// ---------------------------------------------------------------------------
__global__ __launch_bounds__(256) void k_wgemm(const unsigned short* __restrict__ A,
    const unsigned short* __restrict__ Bsrc, unsigned short* __restrict__ out, int orows)
{
    __shared__ __align__(16) char As[8192];
    __shared__ __align__(16) char Bs[8192];
    const int t = threadIdx.x;
    const int l = t & 63, w = t >> 6, wm = w >> 1, wn = w & 1, lr = l & 15, lq = l >> 4;
    const int b  = blockIdx.x >> 9;
    const int ct = (blockIdx.x >> 7) & 3;
    const int nt = blockIdx.x & 127;
    const int c0 = ct*64, n0 = nt*64;

    f32x4 acc[2][2] = {};
    for (int ks = 0; ks < 4; ++ks){
        stage64(A + (size_t)c0*256 + ks*64, 256, As, t);
        stage64(Bsrc + ((size_t)(b*NN + n0))*256 + ks*64, 256, Bs, t);
        __syncthreads();
        mfma8(As, Bs, acc, wm, wn, lr, lq);
        __syncthreads();
    }
    #pragma unroll
    for (int mi = 0; mi < 2; ++mi)
        #pragma unroll
        for (int ni = 0; ni < 2; ++ni)
            #pragma unroll
            for (int r = 0; r < 4; ++r){
                int c = c0 + wm*32 + mi*16 + lq*4 + r;
                int n = n0 + wn*32 + ni*16 + lr;
                out[((size_t)(b*orows + c))*NN + n] = f2bu(acc[mi][ni][r]);
            }
}

// ---------------------------------------------------------------------------
// qk: t = Wqk*x (128xN), proj = Psm_t * t (2x 64xN), FAVOR+ features
// grid = 4 * 128nt = 512
// ---------------------------------------------------------------------------
__global__ __launch_bounds__(256) void k_qk(const unsigned short* __restrict__ Wqk,
    const unsigned short* __restrict__ xT, const unsigned short* __restrict__ Psm_t,
    unsigned short* __restrict__ qp, unsigned short* __restrict__ kp_t)
{
    __shared__ __align__(16) char As[16384];
    __shared__ __align__(16) char Bs[8192];
    __shared__ __align__(16) char Ts[16384];
    __shared__ __align__(16) char Ps[8192];
    const int t = threadIdx.x;
    const int l = t & 63, w = t >> 6, wm = w >> 1, wn = w & 1, lr = l & 15, lq = l >> 4;
    const int b  = blockIdx.x >> 7;
    const int nt = blockIdx.x & 127;
    const int n0 = nt*64;

    stage64(Psm_t, 64, Ps, t);

    f32x4 acc[4][2] = {};
    for (int ks = 0; ks < 4; ++ks){
        #pragma unroll
        for (int i = 0; i < 4; ++i){
            int id = t + 256*i; int row = id >> 3, q = id & 7;
            short8v v = *(const short8v*)(Wqk + (size_t)row*256 + ks*64 + q*8);
            *(short8v*)(As + swz128(row, q*16)) = v;
        }
        stage64(xT + ((size_t)(b*NN + n0))*256 + ks*64, 256, Bs, t);
        __syncthreads();
        #pragma unroll
        for (int kk = 0; kk < 2; ++kk){
            short8v b0 = fld(Bs, wn*32 + lr,      kk*64 + lq*16);
            short8v b1 = fld(Bs, wn*32 + 16 + lr, kk*64 + lq*16);
            #pragma unroll
            for (int mi = 0; mi < 4; ++mi){
                short8v a = fld(As, wm*64 + mi*16 + lr, kk*64 + lq*16);
                acc[mi][0] = MFMA16(a, b0, acc[mi][0], 0, 0, 0);
                acc[mi][1] = MFMA16(a, b1, acc[mi][1], 0, 0, 0);
            }
        }
        __syncthreads();
    }
    // t -> Ts [n][128] bf16 (256B rows, swizzled)
    #pragma unroll
    for (int mi = 0; mi < 4; ++mi)
        #pragma unroll
        for (int ni = 0; ni < 2; ++ni){
            int op = (wm*64 + mi*16 + lq*4)*2;
            int nrow = wn*32 + ni*16 + lr;
            *(unsigned int*)(Ts + swz256(nrow, op))     = pack2(acc[mi][ni][0], acc[mi][ni][1]);
            *(unsigned int*)(Ts + swz256(nrow, op + 4)) = pack2(acc[mi][ni][2], acc[mi][ni][3]);
        }
    __syncthreads();

    const float inv128 = 0.08838834764831845f;
    for (int p = 0; p < 2; ++p){
        f32x4 ac[4] = {};
        #pragma unroll
        for (int kk = 0; kk < 2; ++kk){
            short8v bf = *(const short8v*)(Ts + swz256(w*16 + lr, p*128 + kk*64 + lq*16));
            #pragma unroll
            for (int mi = 0; mi < 4; ++mi){
                short8v a = *(const short8v*)(Ps + swz128(mi*16 + lr, kk*64 + lq*16));
                ac[mi] = MFMA16(a, bf, ac[mi], 0, 0, 0);
            }
        }
        float mx = 0.f;
        #pragma unroll
        for (int mi = 0; mi < 4; ++mi)
            #pragma unroll
            for (int r = 0; r < 4; ++r) mx = fmaxf(mx, fabsf(ac[mi][r]));
        mx = fmaxf(mx, __shfl_xor(mx, 16));
        mx = fmaxf(mx, __shfl_xor(mx, 32));
        const int n = n0 + w*16 + lr;
        if (p == 0){
            unsigned short* qr = qp + ((size_t)(b*NN + n))*RSM;
            #pragma unroll
            for (int mi = 0; mi < 4; ++mi){
                float e0 = __expf( ac[mi][0]-mx)*inv128 + 1e-6f;
                float e1 = __expf( ac[mi][1]-mx)*inv128 + 1e-6f;
                float e2 = __expf( ac[mi][2]-mx)*inv128 + 1e-6f;
                float e3 = __expf( ac[mi][3]-mx)*inv128 + 1e-6f;
                float g0 = __expf(-ac[mi][0]-mx)*inv128 + 1e-6f;
                float g1 = __expf(-ac[mi][1]-mx)*inv128 + 1e-6f;
                float g2 = __expf(-ac[mi][2]-mx)*inv128 + 1e-6f;
                float g3 = __expf(-ac[mi][3]-mx)*inv128 + 1e-6f;
                int i0 = mi*16 + lq*4;
                uint2 pu; pu.x = pack2(e0, e1); pu.y = pack2(e2, e3);
                uint2 nu; nu.x = pack2(g0, g1); nu.y = pack2(g2, g3);
                *(uint2*)(void*)(qr + i0)      = pu;
                *(uint2*)(void*)(qr + 64 + i0) = nu;
            }
        } else {
            unsigned short* kb = kp_t + (size_t)(b*RSM)*NN + n;
            #pragma unroll
            for (int mi = 0; mi < 4; ++mi){
                int i0 = mi*16 + lq*4;
                #pragma unroll
                for (int r = 0; r < 4; ++r){
                    kb[(size_t)(i0 + r)*NN]      = f2bu(__expf( ac[mi][r]-mx)*inv128 + 1e-6f);
                    kb[(size_t)(i0 + r + 64)*NN] = f2bu(__expf(-ac[mi][r]-mx)*inv128 + 1e-6f);
                }
            }
        }
    }
}

// ---------------------------------------------------------------------------
// GeoRFF phi -> phi_row [B][N][16] bf16 + phi_t [B][16][N] bf16 ; grid=128
// ---------------------------------------------------------------------------
__global__ __launch_bounds__(256) void k_phi(const float* __restrict__ pos,
    const float* __restrict__ Wg1, const float* __restrict__ bg1,
    const float* __restrict__ Wg2, const float* __restrict__ bg2,
    const float* __restrict__ log_tau, const float* __restrict__ omega,
    unsigned short* __restrict__ phi_row, unsigned short* __restrict__ phi_t)
{
    const int t = threadIdx.x;
    const int b = blockIdx.x >> 5;
    const int n = ((blockIdx.x & 31) << 8) + t;
    const float* pp = pos + ((size_t)(b*NN + n))*3;
    const float p0 = pp[0], p1 = pp[1], p2 = pp[2];
    float hb[16];
    #pragma unroll
    for (int i = 0; i < 16; ++i)
        hb[i] = fmaxf(0.f, fmaf(Wg1[i*3+0], p0, fmaf(Wg1[i*3+1], p1, fmaf(Wg1[i*3+2], p2, bg1[i]))));
    const float tau = log1pf(__expf(log_tau[0])) + 1e-6f;
    const float sc  = sqrtf(2.f*tau);
    float z[16]; float zn = 0.f;
    #pragma unroll
    for (int i = 0; i < 16; ++i){
        float g = bg2[i];
        #pragma unroll
        for (int j = 0; j < 16; ++j) g = fmaf(Wg2[i*16+j], hb[j], g);
        z[i] = sc*g; zn = fmaf(z[i], z[i], zn);
    }
    zn *= 0.5f;
    float val[16];
    #pragma unroll
    for (int m = 0; m < 16; ++m){
        float s = 0.f;
        #pragma unroll
        for (int i = 0; i < 16; ++i) s = fmaf(z[i], omega[i*16+m], s);
        val[m] = __expf(s - zn)*0.25f;
    }
    unsigned short* pr = phi_row + ((size_t)(b*NN + n))*16;
    u32x4 o0, o1;
    #pragma unroll
    for (int j2 = 0; j2 < 4; ++j2){
        o0[j2] = pack2(val[j2*2], val[j2*2+1]);
        o1[j2] = pack2(val[8+j2*2], val[8+j2*2+1]);
    }
    *(u32x4*)(void*)pr = o0;
    *(u32x4*)(void*)(pr + 8) = o1;
    #pragma unroll
    for (int m = 0; m < 16; ++m)
        phi_t[((size_t)(b*RGEO + m))*NN + n] = f2bu(val[m]);
}

// ---------------------------------------------------------------------------
// kv partial: K-split x4, f32 atomic accumulation into kv_f32
// kv[b][c][r] = sum_n v_t[c][n]*Phik[n][r]   (c=256 row gives ksum)
// grid = 4b * 4ksl * 5ct * 32rt = 2560
// ---------------------------------------------------------------------------
__global__ __launch_bounds__(256) void k_kv(const unsigned short* __restrict__ kp_t,
    const unsigned short* __restrict__ phi_t, const unsigned short* __restrict__ v_t,
    float* __restrict__ kv_f32)
{
    __shared__ __align__(16) char As[8192];
    __shared__ __align__(16) char Bs[8192];
    const int t = threadIdx.x;
    const int l = t & 63, w = t >> 6, wm = w >> 1, wn = w & 1, lr = l & 15, lq = l >> 4;
    const int bid = blockIdx.x;
    const int b   = bid / 640;
    const int rem = bid % 640;
    const int ksl = rem / 160;      // K-slice 0..3
    const int rr  = rem % 160;
    const int ct = rr >> 5, rt = rr & 31;
    const int c0 = ct*64, r0 = rt*64;
    const int rl = t >> 2, u = t & 3;
    const int rg = r0 + rl;
    const unsigned short* kpr = kp_t + ((size_t)(b*RSM  + (rg >> 4)))*NN;
    const unsigned short* phr = phi_t + ((size_t)(b*RGEO + (rg & 15)))*NN;

    f32x4 acc[2][2] = {};
    for (int ks = ksl*32; ks < ksl*32 + 32; ++ks){
        const int nk = ks*64;
        stage64(v_t + ((size_t)(b*320 + c0))*NN + nk, NN, As, t);
        {
            const int nb = nk + u*16;
            short8v k0 = *(const short8v*)(kpr + nb);
            short8v k1 = *(const short8v*)(kpr + nb + 8);
            short8v q0 = *(const short8v*)(phr + nb);
            short8v q1 = *(const short8v*)(phr + nb + 8);
            u32x4 o0, o1;
            #pragma unroll
            for (int j2 = 0; j2 < 4; ++j2){
                o0[j2] = pack2(bu2f((unsigned short)k0[j2*2])  *bu2f((unsigned short)q0[j2*2]),
                               bu2f((unsigned short)k0[j2*2+1])*bu2f((unsigned short)q0[j2*2+1]));
                o1[j2] = pack2(bu2f((unsigned short)k1[j2*2])  *bu2f((unsigned short)q1[j2*2]),
                               bu2f((unsigned short)k1[j2*2+1])*bu2f((unsigned short)q1[j2*2+1]));
            }
            *(u32x4*)(Bs + swz128(rl, u*32))      = o0;
            *(u32x4*)(Bs + swz128(rl, u*32 + 16)) = o1;
        }
        __syncthreads();
        mfma8(As, Bs, acc, wm, wn, lr, lq);
        __syncthreads();
    }
    #pragma unroll
    for (int mi = 0; mi < 2; ++mi)
        #pragma unroll
        for (int ni = 0; ni < 2; ++ni)
            #pragma unroll
            for (int r = 0; r < 4; ++r){
                int c = c0 + wm*32 + mi*16 + lq*4 + r;
                int rg2 = r0 + wn*32 + ni*16 + lr;
                atomicAdd(&kv_f32[((size_t)(b*320 + c))*2048 + rg2], acc[mi][ni][r]);
            }
}

// kv_f32 -> kv_t bf16 ; grid = 2560
__global__ __launch_bounds__(256) void k_kvred(const float* __restrict__ kv_f32,
    unsigned short* __restrict__ kv_t)
{
    const size_t i = ((size_t)blockIdx.x*256 + threadIdx.x)*4;
    f32x4 v = *(const f32x4*)(kv_f32 + i);
    uint2 o; o.x = pack2(v[0], v[1]); o.y = pack2(v[2], v[3]);
    *(uint2*)(void*)(kv_t + i) = o;
}

// ---------------------------------------------------------------------------
// den[b][n] = sum_r qp[n][i]*phi[n][j]*ksum[r] + eps ; grid=128
// ---------------------------------------------------------------------------
__global__ __launch_bounds__(256) void k_denom(const unsigned short* __restrict__ qp,
    const unsigned short* __restrict__ phi_row, const unsigned short* __restrict__ kv_t,
    float* __restrict__ den)
{
    __shared__ float ks[2048];
    const int t = threadIdx.x;
    const int b = blockIdx.x >> 5;
    const int n = ((blockIdx.x & 31) << 8) + t;
    const unsigned short* ksrc = kv_t + ((size_t)(b*320 + 256))*2048;
    #pragma unroll
    for (int i = 0; i < 8; ++i){ int idx = t + 256*i; ks[idx] = bu2f(ksrc[idx]); }
    __syncthreads();
    float phf[16];
    {
        const unsigned short* pr = phi_row + ((size_t)(b*NN + n))*16;
        short8v a = *(const short8v*)pr;
        short8v c = *(const short8v*)(pr + 8);
        #pragma unroll
        for (int j = 0; j < 8; ++j){ phf[j] = bu2f((unsigned short)a[j]); phf[8+j] = bu2f((unsigned short)c[j]); }
    }
    const unsigned short* qr = qp + ((size_t)(b*NN + n))*RSM;
    float acc = 0.f;
    for (int i = 0; i < 128; i += 8){
        short8v qv = *(const short8v*)(qr + i);
        #pragma unroll
        for (int ii = 0; ii < 8; ++ii){
            const float* kk = &ks[(i + ii)*16];
            float s = 0.f;
            #pragma unroll
            for (int j = 0; j < 16; ++j) s = fmaf(phf[j], kk[j], s);
            acc = fmaf(bu2f((unsigned short)qv[ii]), s, acc);
        }
    }
    den[b*NN + n] = acc + 1e-6f;
}

// ---------------------------------------------------------------------------
// fsa^T[c][n] = sum_r kv_t[c][r]*Phiq[n][r] / den ; writes y_nt[n][c]=x-fsa bf16
// grid = 4 * 4ct * 128nt = 2048
// ---------------------------------------------------------------------------
__global__ __launch_bounds__(256) void k_fsa(const unsigned short* __restrict__ kv_t,
    const unsigned short* __restrict__ qp, const unsigned short* __restrict__ phi_row,
    const float* __restrict__ den, const unsigned short* __restrict__ xT,
    unsigned short* __restrict__ y_nt)
{
    __shared__ __align__(16) char As[8192];
    __shared__ __align__(16) char Bs[8192];
    __shared__ __align__(16) char Ys[8192];
    const int t = threadIdx.x;
    const int l = t & 63, w = t >> 6, wm = w >> 1, wn = w & 1, lr = l & 15, lq = l >> 4;
    const int b  = blockIdx.x >> 9;
    const int ct = (blockIdx.x >> 7) & 3;
    const int nt = blockIdx.x & 127;
    const int c0 = ct*64, n0 = nt*64;
    const int nl = t >> 2, u = t & 3;

    float phf[16];
    {
        const unsigned short* pr = phi_row + ((size_t)(b*NN + n0 + nl))*16;
        short8v a = *(const short8v*)pr;
        short8v c = *(const short8v*)(pr + 8);
        #pragma unroll
        for (int j = 0; j < 8; ++j){ phf[j] = bu2f((unsigned short)a[j]); phf[8+j] = bu2f((unsigned short)c[j]); }
    }
    const unsigned short* qprow = qp + ((size_t)(b*NN + n0 + nl))*RSM;

    f32x4 acc[2][2] = {};
    for (int ks = 0; ks < 32; ++ks){
        stage64(kv_t + ((size_t)(b*320 + c0))*2048 + ks*64, 2048, As, t);
        {
            float qv = bu2f(qprow[ks*4 + u]);
            u32x4 o0, o1;
            #pragma unroll
            for (int j2 = 0; j2 < 4; ++j2){
                o0[j2] = pack2(qv*phf[j2*2],     qv*phf[j2*2+1]);
                o1[j2] = pack2(qv*phf[8+j2*2],   qv*phf[8+j2*2+1]);
            }
            *(u32x4*)(Bs + swz128(nl, u*32))      = o0;
            *(u32x4*)(Bs + swz128(nl, u*32 + 16)) = o1;
        }
        __syncthreads();
        mfma8(As, Bs, acc, wm, wn, lr, lq);
        __syncthreads();
    }
    #pragma unroll
    for (int ni = 0; ni < 2; ++ni){
        float rd = 1.0f / den[(size_t)b*NN + n0 + wn*32 + ni*16 + lr];
        #pragma unroll
        for (int mi = 0; mi < 2; ++mi){
            int cb = (wm*32 + mi*16 + lq*4)*2;
            int nrow = wn*32 + ni*16 + lr;
            *(unsigned int*)(Ys + swz128(nrow, cb))     = pack2(acc[mi][ni][0]*rd, acc[mi][ni][1]*rd);
            *(unsigned int*)(Ys + swz128(nrow, cb + 4)) = pack2(acc[mi][ni][2]*rd, acc[mi][ni][3]*rd);
        }
    }
    __syncthreads();
    #pragma unroll
    for (int i = 0; i < 2; ++i){
        int q = u + i*4;
        short8v fs = *(const short8v*)(Ys + swz128(nl, q*16));
        short8v xv = *(const short8v*)(xT + ((size_t)(b*NN + n0 + nl))*CC + c0 + q*8);
        u32x4 o;
        #pragma unroll
        for (int j2 = 0; j2 < 4; ++j2){
            float y0 = bu2f((unsigned short)xv[j2*2])   - bu2f((unsigned short)fs[j2*2]);
            float y1 = bu2f((unsigned short)xv[j2*2+1]) - bu2f((unsigned short)fs[j2*2+1]);
            o[j2] = pack2(y0, y1);
        }
        *(u32x4*)(void*)(y_nt + ((size_t)(b*NN + n0 + nl))*CC + c0 + q*8) = o;
    }
}

// ---------------------------------------------------------------------------
// BN stats per channel ; grid=256
// ---------------------------------------------------------------------------
__global__ __launch_bounds__(256) void k_bnstat(const unsigned short* __restrict__ h,
    const float* __restrict__ gamma, const float* __restrict__ beta, float* __restrict__ bn)
{
    __shared__ float s1[256], s2[256];
    const int t = threadIdx.x, c = blockIdx.x;
    float a1 = 0.f, a2 = 0.f;
    for (int b = 0; b < 4; ++b){
        const unsigned short* hr = h + ((size_t)(b*CC + c))*NN;
        #pragma unroll
        for (int i = 0; i < 4; ++i){
            short8v v = *(const short8v*)(hr + (t + i*256)*8);
            #pragma unroll
            for (int j = 0; j < 8; ++j){ float f = bu2f((unsigned short)v[j]); a1 += f; a2 = fmaf(f, f, a2); }
        }
    }
    s1[t] = a1; s2[t] = a2; __syncthreads();
    for (int st = 128; st > 0; st >>= 1){
        if (t < st){ s1[t] += s1[t + st]; s2[t] += s2[t + st]; }
        __syncthreads();
    }
    if (t == 0){
        float inv = 1.f/32768.f;
        float mean = s1[0]*inv, var = s2[0]*inv - mean*mean;
        float sc = gamma[c]*rsqrtf(var + 1e-5f);
        bn[512 + c] = sc; bn[768 + c] = fmaf(-mean, sc, beta[c]);
    }
}

// ---------------------------------------------------------------------------
// out = relu(h*s+b) + x ; grid=2048
// ---------------------------------------------------------------------------
__global__ __launch_bounds__(256) void k_apply(const unsigned short* __restrict__ h,
    const float* __restrict__ x, const float* __restrict__ bn, float* __restrict__ out)
{
    const size_t tot8 = (size_t)BB*CC*NN/8;
    for (size_t i = (size_t)blockIdx.x*256 + threadIdx.x; i < tot8; i += 2048*256){
        int c = (int)((i >> 10) & 255);
        float s = bn[512 + c], bb = bn[768 + c];
        short8v hv = *(const short8v*)(h + i*8);
        f32x4 x0 = *(const f32x4*)(x + i*8);
        f32x4 x1 = *(const f32x4*)(x + i*8 + 4);
        f32x4 o0, o1;
        #pragma unroll
        for (int j = 0; j < 4; ++j){
            o0[j] = fmaxf(fmaf(bu2f((unsigned short)hv[j]),     s, bb), 0.f) + x0[j];
            o1[j] = fmaxf(fmaf(bu2f((unsigned short)hv[4 + j]), s, bb), 0.f) + x1[j];
        }
        *(f32x4*)(out + i*8)     = o0;
        *(f32x4*)(out + i*8 + 4) = o1;
    }
}

extern "C" void kernel_launch(void* const* d_in, const int* in_sizes, int n_in,
                              void* d_out, int out_size, void* d_ws, size_t ws_size,
                              hipStream_t stream)
{
    (void)in_sizes; (void)n_in; (void)out_size; (void)ws_size;
    const float* x       = (const float*)d_in[0];
    const float* pos     = (const float*)d_in[1];
    const float* Wq      = (const float*)d_in[2];
    const float* Wk      = (const float*)d_in[3];
    const float* Wv      = (const float*)d_in[4];
    const float* Psm     = (const float*)d_in[5];
    const float* Wg1     = (const float*)d_in[6];
    const float* bg1     = (const float*)d_in[7];
    const float* Wg2     = (const float*)d_in[8];
    const float* bg2     = (const float*)d_in[9];
    const float* log_tau = (const float*)d_in[10];
    const float* omega   = (const float*)d_in[11];
    const float* Wp      = (const float*)d_in[12];
    const float* gamma   = (const float*)d_in[13];
    const float* beta    = (const float*)d_in[14];
    char* W = (char*)d_ws;
    float* out = (float*)d_out;

    unsigned short* qp    = (unsigned short*)(W + P_QP);
    unsigned short* kp_t  = (unsigned short*)(W + P_KPT);
    unsigned short* phir  = (unsigned short*)(W + P_PHIR);
    unsigned short* phit  = (unsigned short*)(W + P_PHIT);
    unsigned short* xT    = (unsigned short*)(W + P_XT);
    unsigned short* v_t   = (unsigned short*)(W + P_VT);
    unsigned short* y_nt  = (unsigned short*)(W + P_YNT);
    unsigned short* kv_t  = (unsigned short*)(W + P_KVT);
    float*          den   = (float*)(W + P_DEN);
    unsigned short* Wqk_b = (unsigned short*)(W + P_WQK);
    unsigned short* Wv_b  = (unsigned short*)(W + P_WV);
    unsigned short* Wp_b  = (unsigned short*)(W + P_WP);
    unsigned short* Psm_t = (unsigned short*)(W + P_PSMT);
    float*          bn    = (float*)(W + P_BN);
    float*          kvf   = (float*)(W + P_KVF);
    unsigned short* hbuf  = (unsigned short*)(W + P_H);

    hipMemsetAsync(W + P_KVF, 0, 10485760, stream);
    k_prep  <<<  64, 256, 0, stream>>>(Wq, Wk, Wv, Wp, Psm, Wqk_b, Wv_b, Wp_b, Psm_t, v_t);
    k_xt    <<<2048, 256, 0, stream>>>(x, xT);
    k_wgemm <<<2048, 256, 0, stream>>>(Wv_b, xT, v_t, 320);
    k_qk    <<< 512, 256, 0, stream>>>(Wqk_b, xT, Psm_t, qp, kp_t);
    k_phi   <<< 128, 256, 0, stream>>>(pos, Wg1, bg1, Wg2, bg2, log_tau, omega, phir, phit);
    k_kv    <<<2560, 256, 0, stream>>>(kp_t, phit, v_t, kvf);
    k_kvred <<<2560, 256, 0, stream>>>(kvf, kv_t);
    k_denom <<< 128, 256, 0, stream>>>(qp, phir, kv_t, den);
    k_fsa   <<<2048, 256, 0, stream>>>(kv_t, qp, phir, den, xT, y_nt);
    k_wgemm <<<2048, 256, 0, stream>>>(Wp_b, y_nt, hbuf, 256);
    k_bnstat<<< 256, 256, 0, stream>>>(hbuf, gamma, beta, bn);
    k_apply <<<2048, 256, 0, stream>>>(hbuf, x, bn, out);
}

// Round 5
// 330.030 us; speedup vs baseline: 12.1105x; 1.0717x over previous
//
#include <hip/hip_runtime.h>
#include <hip/hip_bf16.h>
#include <math.h>

#define BB 4
#define CC 256
#define NN 8192
#define RSM 128
#define RGEO 16

typedef __attribute__((ext_vector_type(8))) short short8v;
typedef __attribute__((ext_vector_type(4))) float f32x4;
typedef __attribute__((ext_vector_type(4))) unsigned int u32x4;

#define MFMA16 __builtin_amdgcn_mfma_f32_16x16x32_bf16

// ---- workspace byte offsets (peak 65.5 MB; ws >= 72.8 MB proven in r2/r4) ----
#define P_QP   0ull          // qp  [B][N][128] bf16   (8 MB)
#define P_KPT  8388608ull    // kp_t[B][128][N] bf16   (8 MB)
#define P_PHIR 16777216ull   // phi_row [B][N][16] bf16 (1 MB)
#define P_PHIT 17825792ull   // phi_t [B][16][N] bf16   (1 MB)
#define P_XT   18874368ull   // x^T bf16 [B][N][256]   (16 MB)
#define P_VT   35651584ull   // v_t [B][256][N] bf16   (16 MB)
#define P_YNT  35651584ull   // y_nt [B][N][256] bf16  (16 MB, overlays v_t after k_kv)
#define P_KVT  52428800ull   // kv_t bf16 [B][256][2048] (4 MB)
#define P_KVF  56623104ull   // kv_f32 [B][256][2048] f32 (8 MB)
#define P_KSUM 65011712ull   // ksum f32 [B][2048] (32 KB)
#define P_DEN  65044480ull   // den [B][N] f32 (128 KB)
#define P_WQK  65175552ull   // Wqk bf16 [128][256]
#define P_WV   65241088ull   // Wv  bf16 [256][256]
#define P_WP   65372160ull   // Wp  bf16 [256][256]
#define P_PSMT 65503232ull   // Psm^T*scale bf16 [64][64]
#define P_BN   65511424ull   // bn f32 [1024]
#define P_H    0ull          // h bf16 [B][256][N] (16 MB, overlays qp+kp_t after k_fsa)

__device__ __forceinline__ unsigned short f2bu(float f){
    __hip_bfloat16 h = __float2bfloat16(f);
    return __builtin_bit_cast(unsigned short, h);
}
__device__ __forceinline__ float bu2f(unsigned short u){
    return __builtin_bit_cast(float, ((unsigned int)u) << 16);
}
__device__ __forceinline__ unsigned int pack2(float a, float b){
    return (unsigned int)f2bu(a) | (((unsigned int)f2bu(b)) << 16);
}
__device__ __forceinline__ int swz128(int row, int cb){ return (row*128 + cb) ^ ((row & 7) << 4); }
__device__ __forceinline__ int swz256(int row, int cb){ return (row*256 + cb) ^ ((row & 7) << 4); }

// stage a 64-row x 64-elem bf16 tile into swizzled LDS (128B rows)
__device__ __forceinline__ void stage64(const unsigned short* __restrict__ g, size_t stride,
                                        char* lds, int t){
    #pragma unroll
    for (int i = 0; i < 2; ++i){
        int id = t + 256*i; int row = id >> 3, q = id & 7;
        short8v v = *(const short8v*)(g + (size_t)row*stride + q*8);
        *(short8v*)(lds + swz128(row, q*16)) = v;
    }
}
// stage a 128-row x 64-elem bf16 tile
__device__ __forceinline__ void stage128(const unsigned short* __restrict__ g, size_t stride,
                                         char* lds, int t){
    #pragma unroll
    for (int i = 0; i < 4; ++i){
        int id = t + 256*i; int row = id >> 3, q = id & 7;
        short8v v = *(const short8v*)(g + (size_t)row*stride + q*8);
        *(short8v*)(lds + swz128(row, q*16)) = v;
    }
}
__device__ __forceinline__ short8v fld(const char* lds, int row, int cb){
    return *(const short8v*)(lds + swz128(row, cb));
}
// legacy 2x2 step (k_wgemm): 4 waves as 2x2, each wave 32x32
__device__ __forceinline__ void mfma8(const char* As, const char* Bs, f32x4 acc[2][2],
                                      int wm, int wn, int lr, int lq){
    #pragma unroll
    for (int kk = 0; kk < 2; ++kk){
        short8v a0 = fld(As, wm*32 + lr,      kk*64 + lq*16);
        short8v a1 = fld(As, wm*32 + 16 + lr, kk*64 + lq*16);
        short8v b0 = fld(Bs, wn*32 + lr,      kk*64 + lq*16);
        short8v b1 = fld(Bs, wn*32 + 16 + lr, kk*64 + lq*16);
        acc[0][0] = MFMA16(a0, b0, acc[0][0], 0, 0, 0);
        acc[0][1] = MFMA16(a0, b1, acc[0][1], 0, 0, 0);
        acc[1][0] = MFMA16(a1, b0, acc[1][0], 0, 0, 0);
        acc[1][1] = MFMA16(a1, b1, acc[1][1], 0, 0, 0);
    }
}
// 4x4-frag step: wave = 64x64, 8 reads -> 16 MFMA per kk
__device__ __forceinline__ void mfma16s(const char* As, const char* Bs, f32x4 acc[4][4],
                                        int wm, int wn, int lr, int lq){
    #pragma unroll
    for (int kk = 0; kk < 2; ++kk){
        short8v af[4], bf[4];
        #pragma unroll
        for (int f = 0; f < 4; ++f) af[f] = fld(As, wm*64 + f*16 + lr, kk*64 + lq*16);
        #pragma unroll
        for (int f = 0; f < 4; ++f) bf[f] = fld(Bs, wn*64 + f*16 + lr, kk*64 + lq*16);
        #pragma unroll
        for (int fa = 0; fa < 4; ++fa)
            #pragma unroll
            for (int fb = 0; fb < 4; ++fb)
                acc[fa][fb] = MFMA16(af[fa], bf[fb], acc[fa][fb], 0, 0, 0);
    }
}

// ---------------------------------------------------------------------------
// prep: bf16 weight conversion
// ---------------------------------------------------------------------------
__global__ __launch_bounds__(256) void k_prep(const float* __restrict__ Wq, const float* __restrict__ Wk,
    const float* __restrict__ Wv, const float* __restrict__ Wp, const float* __restrict__ Psm,
    unsigned short* __restrict__ Wqk_bf, unsigned short* __restrict__ Wv_bf,
    unsigned short* __restrict__ Wp_bf, unsigned short* __restrict__ Psm_t)
{
    const int tid = blockIdx.x*256 + threadIdx.x;
    const int nth = 64*256;
    for (int i = tid; i < 32768; i += nth){
        int o = i >> 8, c = i & 255;
        Wqk_bf[i] = f2bu(o < 64 ? Wq[o*256 + c] : Wk[(o-64)*256 + c]);
    }
    for (int i = tid; i < 65536; i += nth) Wv_bf[i] = f2bu(Wv[i]);
    for (int i = tid; i < 65536; i += nth) Wp_bf[i] = f2bu(Wp[i]);
    for (int i = tid; i < 4096; i += nth){
        int m = i >> 6, o = i & 63;
        Psm_t[i] = f2bu(Psm[o*64 + m] * 0.35355339059327373f);
    }
}

// ---------------------------------------------------------------------------
// x [B][C][N] f32 -> x^T [B][N][C] bf16
// ---------------------------------------------------------------------------
__global__ __launch_bounds__(256) void k_xt(const float* __restrict__ x, unsigned short* __restrict__ xT)
{
    __shared__ float xs[64][65];
    const int t = threadIdx.x;
    const int b  = blockIdx.x >> 9;
    const int ct = (blockIdx.x >> 7) & 3;
    const int nt = blockIdx.x & 127;
    const int c0 = ct*64, n0 = nt*64;
    #pragma unroll
    for (int i = 0; i < 4; ++i){
        int id = t + 256*i; int row = id >> 4, fq = id & 15;
        f32x4 v = *(const f32x4*)(x + ((size_t)(b*CC + c0 + row))*NN + n0 + fq*4);
        xs[row][fq*4+0] = v[0]; xs[row][fq*4+1] = v[1];
        xs[row][fq*4+2] = v[2]; xs[row][fq*4+3] = v[3];
    }
    __syncthreads();
    #pragma unroll
    for (int i = 0; i < 2; ++i){
        int id = t + 256*i; int n = id >> 3, q = id & 7;
        u32x4 o;
        #pragma unroll
        for (int j2 = 0; j2 < 4; ++j2)
            o[j2] = pack2(xs[q*8 + j2*2][n], xs[q*8 + j2*2+1][n]);
        *(u32x4*)(void*)(xT + ((size_t)(b*NN + n0 + n))*CC + c0 + q*8) = o;
    }
}

// ---------------------------------------------------------------------------
// weight GEMM: out[b][c][n] = sum_k A[c][k] * B[b][n][k]
// grid = 4 * 4ct * 128nt = 2048
// ---------------------------------------------------------------------------
__global__ __launch_bounds__(256) void k_wgemm(const unsigned short* __restrict__ A,
    const unsigned short* __restrict__ Bsrc, unsigned short* __restrict__ out, int orows)
{
    __shared__ __align__(16) char As[8192];
    __shared__ __align__(16) char Bs[8192];
    const int t = threadIdx.x;
    const int l = t & 63, w = t >> 6, wm = w >> 1, wn = w & 1, lr = l & 15, lq = l >> 4;
    const int b  = blockIdx.x >> 9;
    const int ct = (blockIdx.x >> 7) & 3;
    const int nt = blockIdx.x & 127;
    const int c0 = ct*64, n0 = nt*64;

    f32x4 acc[2][2] = {};
    for (int ks = 0; ks < 4; ++ks){
        stage64(A + (size_t)c0*256 + ks*64, 256, As, t);
        stage64(Bsrc + ((size_t)(b*NN + n0))*256 + ks*64, 256, Bs, t);
        __syncthreads();
        mfma8(As, Bs, acc, wm, wn, lr, lq);
        __syncthreads();
    }
    #pragma unroll
    for (int mi = 0; mi < 2; ++mi)
        #pragma unroll
        for (int ni = 0; ni < 2; ++ni)
            #pragma unroll
            for (int r = 0; r < 4; ++r){
                int c = c0 + wm*32 + mi*16 + lq*4 + r;
                int n = n0 + wn*32 + ni*16 + lr;
                out[((size_t)(b*orows + c))*NN + n] = f2bu(acc[mi][ni][r]);
            }
}

// ---------------------------------------------------------------------------
// qk: t = Wqk*x (128xN), proj = Psm_t * t, FAVOR+ features ; grid = 512
// ---------------------------------------------------------------------------
__global__ __launch_bounds__(256) void k_qk(const unsigned short* __restrict__ Wqk,
    const unsigned short* __restrict__ xT, const unsigned short* __restrict__ Psm_t,
    unsigned short* __restrict__ qp, unsigned short* __restrict__ kp_t)
{
    __shared__ __align__(16) char As[16384];
    __shared__ __align__(16) char Bs[8192];
    __shared__ __align__(16) char Ts[16384];
    __shared__ __align__(16) char Ps[8192];
    const int t = threadIdx.x;
    const int l = t & 63, w = t >> 6, wm = w >> 1, wn = w & 1, lr = l & 15, lq = l >> 4;
    const int b  = blockIdx.x >> 7;
    const int nt = blockIdx.x & 127;
    const int n0 = nt*64;

    stage64(Psm_t, 64, Ps, t);

    f32x4 acc[4][2] = {};
    for (int ks = 0; ks < 4; ++ks){
        #pragma unroll
        for (int i = 0; i < 4; ++i){
            int id = t + 256*i; int row = id >> 3, q = id & 7;
            short8v v = *(const short8v*)(Wqk + (size_t)row*256 + ks*64 + q*8);
            *(short8v*)(As + swz128(row, q*16)) = v;
        }
        stage64(xT + ((size_t)(b*NN + n0))*256 + ks*64, 256, Bs, t);
        __syncthreads();
        #pragma unroll
        for (int kk = 0; kk < 2; ++kk){
            short8v b0 = fld(Bs, wn*32 + lr,      kk*64 + lq*16);
            short8v b1 = fld(Bs, wn*32 + 16 + lr, kk*64 + lq*16);
            #pragma unroll
            for (int mi = 0; mi < 4; ++mi){
                short8v a = fld(As, wm*64 + mi*16 + lr, kk*64 + lq*16);
                acc[mi][0] = MFMA16(a, b0, acc[mi][0], 0, 0, 0);
                acc[mi][1] = MFMA16(a, b1, acc[mi][1], 0, 0, 0);
            }
        }
        __syncthreads();
    }
    #pragma unroll
    for (int mi = 0; mi < 4; ++mi)
        #pragma unroll
        for (int ni = 0; ni < 2; ++ni){
            int op = (wm*64 + mi*16 + lq*4)*2;
            int nrow = wn*32 + ni*16 + lr;
            *(unsigned int*)(Ts + swz256(nrow, op))     = pack2(acc[mi][ni][0], acc[mi][ni][1]);
            *(unsigned int*)(Ts + swz256(nrow, op + 4)) = pack2(acc[mi][ni][2], acc[mi][ni][3]);
        }
    __syncthreads();

    const float inv128 = 0.08838834764831845f;
    for (int p = 0; p < 2; ++p){
        f32x4 ac[4] = {};
        #pragma unroll
        for (int kk = 0; kk < 2; ++kk){
            short8v bf = *(const short8v*)(Ts + swz256(w*16 + lr, p*128 + kk*64 + lq*16));
            #pragma unroll
            for (int mi = 0; mi < 4; ++mi){
                short8v a = *(const short8v*)(Ps + swz128(mi*16 + lr, kk*64 + lq*16));
                ac[mi] = MFMA16(a, bf, ac[mi], 0, 0, 0);
            }
        }
        float mx = 0.f;
        #pragma unroll
        for (int mi = 0; mi < 4; ++mi)
            #pragma unroll
            for (int r = 0; r < 4; ++r) mx = fmaxf(mx, fabsf(ac[mi][r]));
        mx = fmaxf(mx, __shfl_xor(mx, 16));
        mx = fmaxf(mx, __shfl_xor(mx, 32));
        const int n = n0 + w*16 + lr;
        if (p == 0){
            unsigned short* qr = qp + ((size_t)(b*NN + n))*RSM;
            #pragma unroll
            for (int mi = 0; mi < 4; ++mi){
                float e0 = __expf( ac[mi][0]-mx)*inv128 + 1e-6f;
                float e1 = __expf( ac[mi][1]-mx)*inv128 + 1e-6f;
                float e2 = __expf( ac[mi][2]-mx)*inv128 + 1e-6f;
                float e3 = __expf( ac[mi][3]-mx)*inv128 + 1e-6f;
                float g0 = __expf(-ac[mi][0]-mx)*inv128 + 1e-6f;
                float g1 = __expf(-ac[mi][1]-mx)*inv128 + 1e-6f;
                float g2 = __expf(-ac[mi][2]-mx)*inv128 + 1e-6f;
                float g3 = __expf(-ac[mi][3]-mx)*inv128 + 1e-6f;
                int i0 = mi*16 + lq*4;
                uint2 pu; pu.x = pack2(e0, e1); pu.y = pack2(e2, e3);
                uint2 nu; nu.x = pack2(g0, g1); nu.y = pack2(g2, g3);
                *(uint2*)(void*)(qr + i0)      = pu;
                *(uint2*)(void*)(qr + 64 + i0) = nu;
            }
        } else {
            unsigned short* kb = kp_t + (size_t)(b*RSM)*NN + n;
            #pragma unroll
            for (int mi = 0; mi < 4; ++mi){
                int i0 = mi*16 + lq*4;
                #pragma unroll
                for (int r = 0; r < 4; ++r){
                    kb[(size_t)(i0 + r)*NN]      = f2bu(__expf( ac[mi][r]-mx)*inv128 + 1e-6f);
                    kb[(size_t)(i0 + r + 64)*NN] = f2bu(__expf(-ac[mi][r]-mx)*inv128 + 1e-6f);
                }
            }
        }
    }
}

// ---------------------------------------------------------------------------
// GeoRFF phi ; grid=128
// ---------------------------------------------------------------------------
__global__ __launch_bounds__(256) void k_phi(const float* __restrict__ pos,
    const float* __restrict__ Wg1, const float* __restrict__ bg1,
    const float* __restrict__ Wg2, const float* __restrict__ bg2,
    const float* __restrict__ log_tau, const float* __restrict__ omega,
    unsigned short* __restrict__ phi_row, unsigned short* __restrict__ phi_t)
{
    const int t = threadIdx.x;
    const int b = blockIdx.x >> 5;
    const int n = ((blockIdx.x & 31) << 8) + t;
    const float* pp = pos + ((size_t)(b*NN + n))*3;
    const float p0 = pp[0], p1 = pp[1], p2 = pp[2];
    float hb[16];
    #pragma unroll
    for (int i = 0; i < 16; ++i)
        hb[i] = fmaxf(0.f, fmaf(Wg1[i*3+0], p0, fmaf(Wg1[i*3+1], p1, fmaf(Wg1[i*3+2], p2, bg1[i]))));
    const float tau = log1pf(__expf(log_tau[0])) + 1e-6f;
    const float sc  = sqrtf(2.f*tau);
    float z[16]; float zn = 0.f;
    #pragma unroll
    for (int i = 0; i < 16; ++i){
        float g = bg2[i];
        #pragma unroll
        for (int j = 0; j < 16; ++j) g = fmaf(Wg2[i*16+j], hb[j], g);
        z[i] = sc*g; zn = fmaf(z[i], z[i], zn);
    }
    zn *= 0.5f;
    float val[16];
    #pragma unroll
    for (int m = 0; m < 16; ++m){
        float s = 0.f;
        #pragma unroll
        for (int i = 0; i < 16; ++i) s = fmaf(z[i], omega[i*16+m], s);
        val[m] = __expf(s - zn)*0.25f;
    }
    unsigned short* pr = phi_row + ((size_t)(b*NN + n))*16;
    u32x4 o0, o1;
    #pragma unroll
    for (int j2 = 0; j2 < 4; ++j2){
        o0[j2] = pack2(val[j2*2], val[j2*2+1]);
        o1[j2] = pack2(val[8+j2*2], val[8+j2*2+1]);
    }
    *(u32x4*)(void*)pr = o0;
    *(u32x4*)(void*)(pr + 8) = o1;
    #pragma unroll
    for (int m = 0; m < 16; ++m)
        phi_t[((size_t)(b*RGEO + m))*NN + n] = f2bu(val[m]);
}

// ---------------------------------------------------------------------------
// kv: 128c x 128r tile, 4x4 frags/wave; K-split x8 w/ f32 atomics.
// ksum = byproduct of Phi build (ct==0 blocks only).
// grid = 4b x 8ksl x 2ct x 16rt = 1024
// ---------------------------------------------------------------------------
__global__ __launch_bounds__(256) void k_kv(const unsigned short* __restrict__ kp_t,
    const unsigned short* __restrict__ phi_t, const unsigned short* __restrict__ v_t,
    float* __restrict__ kv_f32, float* __restrict__ ksum)
{
    __shared__ __align__(16) char As[16384];   // v   128c x 64n
    __shared__ __align__(16) char Bs[16384];   // Phi 128r x 64n
    const int t = threadIdx.x;
    const int l = t & 63, w = t >> 6, wm = w >> 1, wn = w & 1, lr = l & 15, lq = l >> 4;
    const int bid = blockIdx.x;
    const int rt  = bid & 15;
    const int ct  = (bid >> 4) & 1;
    const int ksl = (bid >> 5) & 7;
    const int b   = bid >> 8;
    const int c0 = ct*128, r0 = rt*128;

    const int brow = t >> 1, half = t & 1;           // Phi-build: 128 rows x 2 halves
    const int rg = r0 + brow;
    const unsigned short* kpr = kp_t + ((size_t)(b*RSM  + (rg >> 4)))*NN;
    const unsigned short* phr = phi_t + ((size_t)(b*RGEO + (rg & 15)))*NN;
    float ksacc = 0.f;

    f32x4 acc[4][4] = {};
    for (int ks = 0; ks < 16; ++ks){
        const int nk = ksl*1024 + ks*64;
        stage128(v_t + ((size_t)(b*CC + c0))*NN + nk, NN, As, t);
        {
            const int nb = nk + half*32;
            #pragma unroll
            for (int c4 = 0; c4 < 2; ++c4){
                short8v k0 = *(const short8v*)(kpr + nb + c4*16);
                short8v k1 = *(const short8v*)(kpr + nb + c4*16 + 8);
                short8v p0 = *(const short8v*)(phr + nb + c4*16);
                short8v p1 = *(const short8v*)(phr + nb + c4*16 + 8);
                float pr0[8], pr1[8];
                #pragma unroll
                for (int e = 0; e < 8; ++e){
                    pr0[e] = bu2f((unsigned short)k0[e])*bu2f((unsigned short)p0[e]);
                    pr1[e] = bu2f((unsigned short)k1[e])*bu2f((unsigned short)p1[e]);
                }
                if (ct == 0){
                    #pragma unroll
                    for (int e = 0; e < 8; ++e) ksacc += pr0[e] + pr1[e];
                }
                u32x4 o0, o1;
                #pragma unroll
                for (int j2 = 0; j2 < 4; ++j2){
                    o0[j2] = pack2(pr0[j2*2], pr0[j2*2+1]);
                    o1[j2] = pack2(pr1[j2*2], pr1[j2*2+1]);
                }
                *(u32x4*)(Bs + swz128(brow, half*64 + c4*32))      = o0;
                *(u32x4*)(Bs + swz128(brow, half*64 + c4*32 + 16)) = o1;
            }
        }
        __syncthreads();
        mfma16s(As, Bs, acc, wm, wn, lr, lq);
        __syncthreads();
    }
    #pragma unroll
    for (int fa = 0; fa < 4; ++fa)
        #pragma unroll
        for (int fb = 0; fb < 4; ++fb)
            #pragma unroll
            for (int e = 0; e < 4; ++e){
                int c = c0 + wm*64 + fa*16 + lq*4 + e;
                int r = r0 + wn*64 + fb*16 + lr;
                atomicAdd(&kv_f32[((size_t)(b*CC + c))*2048 + r], acc[fa][fb][e]);
            }
    if (ct == 0){
        float o = __shfl_xor(ksacc, 1);
        if (half == 0) atomicAdd(&ksum[b*2048 + rg], ksacc + o);
    }
}

// kv_f32 -> kv_t bf16 ; grid = 2048
__global__ __launch_bounds__(256) void k_kvred(const float* __restrict__ kv_f32,
    unsigned short* __restrict__ kv_t)
{
    const size_t i = ((size_t)blockIdx.x*256 + threadIdx.x)*4;
    f32x4 v = *(const f32x4*)(kv_f32 + i);
    uint2 o; o.x = pack2(v[0], v[1]); o.y = pack2(v[2], v[3]);
    *(uint2*)(void*)(kv_t + i) = o;
}

// ---------------------------------------------------------------------------
// den[b][n] = sum_r qp[n][i]*phi[n][j]*ksum[r] + eps ; grid=128
// ---------------------------------------------------------------------------
__global__ __launch_bounds__(256) void k_denom(const unsigned short* __restrict__ qp,
    const unsigned short* __restrict__ phi_row, const float* __restrict__ ksum,
    float* __restrict__ den)
{
    __shared__ float ks[2048];
    const int t = threadIdx.x;
    const int b = blockIdx.x >> 5;
    const int n = ((blockIdx.x & 31) << 8) + t;
    const float* ksrc = ksum + b*2048;
    #pragma unroll
    for (int i = 0; i < 8; ++i){ int idx = t + 256*i; ks[idx] = ksrc[idx]; }
    __syncthreads();
    float phf[16];
    {
        const unsigned short* pr = phi_row + ((size_t)(b*NN + n))*16;
        short8v a = *(const short8v*)pr;
        short8v c = *(const short8v*)(pr + 8);
        #pragma unroll
        for (int j = 0; j < 8; ++j){ phf[j] = bu2f((unsigned short)a[j]); phf[8+j] = bu2f((unsigned short)c[j]); }
    }
    const unsigned short* qr = qp + ((size_t)(b*NN + n))*RSM;
    float acc = 0.f;
    for (int i = 0; i < 128; i += 8){
        short8v qv = *(const short8v*)(qr + i);
        #pragma unroll
        for (int ii = 0; ii < 8; ++ii){
            const float* kk = &ks[(i + ii)*16];
            float s = 0.f;
            #pragma unroll
            for (int j = 0; j < 16; ++j) s = fmaf(phf[j], kk[j], s);
            acc = fmaf(bu2f((unsigned short)qv[ii]), s, acc);
        }
    }
    den[b*NN + n] = acc + 1e-6f;
}

// ---------------------------------------------------------------------------
// fsa: 128c x 128n tile, 4x4 frags/wave; K = r = 2048.
// writes y_nt[n][c] = x - fsa/den. grid = 4b x 2ct x 64nt = 512
// ---------------------------------------------------------------------------
__global__ __launch_bounds__(256) void k_fsa(const unsigned short* __restrict__ kv_t,
    const unsigned short* __restrict__ qp, const unsigned short* __restrict__ phi_row,
    const float* __restrict__ den, const unsigned short* __restrict__ xT,
    unsigned short* __restrict__ y_nt)
{
    __shared__ __align__(16) char Sm[32768];   // As 16K | Bs 16K ; Ys overlays all
    char* As = Sm;
    char* Bs = Sm + 16384;
    const int t = threadIdx.x;
    const int l = t & 63, w = t >> 6, wm = w >> 1, wn = w & 1, lr = l & 15, lq = l >> 4;
    const int nt = blockIdx.x & 63;
    const int ct = (blockIdx.x >> 6) & 1;
    const int b  = blockIdx.x >> 7;
    const int c0 = ct*128, n0 = nt*128;

    const int brow = t >> 1, half = t & 1;     // Phi_q build: 128 n-rows x 2 halves
    float phf[16];
    {
        const unsigned short* pr = phi_row + ((size_t)(b*NN + n0 + brow))*16;
        short8v a = *(const short8v*)pr;
        short8v c = *(const short8v*)(pr + 8);
        #pragma unroll
        for (int j = 0; j < 8; ++j){ phf[j] = bu2f((unsigned short)a[j]); phf[8+j] = bu2f((unsigned short)c[j]); }
    }
    const unsigned short* qrow = qp + ((size_t)(b*NN + n0 + brow))*RSM;

    f32x4 acc[4][4] = {};
    for (int ks = 0; ks < 32; ++ks){
        const int rk = ks*64;
        stage128(kv_t + ((size_t)(b*CC + c0))*2048 + rk, 2048, As, t);
        {
            const int ib = (rk >> 4) + half*2;
            const float q0 = bu2f(qrow[ib]);
            const float q1 = bu2f(qrow[ib + 1]);
            u32x4 oa, ob;
            #pragma unroll
            for (int j2 = 0; j2 < 4; ++j2){
                oa[j2] = pack2(q0*phf[j2*2],     q0*phf[j2*2+1]);
                ob[j2] = pack2(q0*phf[8+j2*2],   q0*phf[8+j2*2+1]);
            }
            *(u32x4*)(Bs + swz128(brow, half*64))      = oa;
            *(u32x4*)(Bs + swz128(brow, half*64 + 16)) = ob;
            #pragma unroll
            for (int j2 = 0; j2 < 4; ++j2){
                oa[j2] = pack2(q1*phf[j2*2],     q1*phf[j2*2+1]);
                ob[j2] = pack2(q1*phf[8+j2*2],   q1*phf[8+j2*2+1]);
            }
            *(u32x4*)(Bs + swz128(brow, half*64 + 32)) = oa;
            *(u32x4*)(Bs + swz128(brow, half*64 + 48)) = ob;
        }
        __syncthreads();
        mfma16s(As, Bs, acc, wm, wn, lr, lq);
        __syncthreads();
    }
    // divide + stage to Ys (overlays Sm), rows = n (256B), cols = c
    float rd[4];
    #pragma unroll
    for (int fb = 0; fb < 4; ++fb)
        rd[fb] = 1.0f / den[(size_t)b*NN + n0 + wn*64 + fb*16 + lr];
    #pragma unroll
    for (int fa = 0; fa < 4; ++fa)
        #pragma unroll
        for (int fb = 0; fb < 4; ++fb){
            int nrow = wn*64 + fb*16 + lr;
            int cb   = (wm*64 + fa*16 + lq*4)*2;
            *(unsigned int*)(Sm + swz256(nrow, cb))     = pack2(acc[fa][fb][0]*rd[fb], acc[fa][fb][1]*rd[fb]);
            *(unsigned int*)(Sm + swz256(nrow, cb + 4)) = pack2(acc[fa][fb][2]*rd[fb], acc[fa][fb][3]*rd[fb]);
        }
    __syncthreads();
    #pragma unroll
    for (int i = 0; i < 8; ++i){
        int id = t + 256*i; int row = id >> 4, q = id & 15;
        short8v fs = *(const short8v*)(Sm + swz256(row, q*16));
        short8v xv = *(const short8v*)(xT + ((size_t)(b*NN + n0 + row))*CC + c0 + q*8);
        u32x4 o;
        #pragma unroll
        for (int j2 = 0; j2 < 4; ++j2){
            float y0 = bu2f((unsigned short)xv[j2*2])   - bu2f((unsigned short)fs[j2*2]);
            float y1 = bu2f((unsigned short)xv[j2*2+1]) - bu2f((unsigned short)fs[j2*2+1]);
            o[j2] = pack2(y0, y1);
        }
        *(u32x4*)(void*)(y_nt + ((size_t)(b*NN + n0 + row))*CC + c0 + q*8) = o;
    }
}

// ---------------------------------------------------------------------------
// BN stats per channel ; grid=256
// ---------------------------------------------------------------------------
__global__ __launch_bounds__(256) void k_bnstat(const unsigned short* __restrict__ h,
    const float* __restrict__ gamma, const float* __restrict__ beta, float* __restrict__ bn)
{
    __shared__ float s1[256], s2[256];
    const int t = threadIdx.x, c = blockIdx.x;
    float a1 = 0.f, a2 = 0.f;
    for (int b = 0; b < 4; ++b){
        const unsigned short* hr = h + ((size_t)(b*CC + c))*NN;
        #pragma unroll
        for (int i = 0; i < 4; ++i){
            short8v v = *(const short8v*)(hr + (t + i*256)*8);
            #pragma unroll
            for (int j = 0; j < 8; ++j){ float f = bu2f((unsigned short)v[j]); a1 += f; a2 = fmaf(f, f, a2); }
        }
    }
    s1[t] = a1; s2[t] = a2; __syncthreads();
    for (int st = 128; st > 0; st >>= 1){
        if (t < st){ s1[t] += s1[t + st]; s2[t] += s2[t + st]; }
        __syncthreads();
    }
    if (t == 0){
        float inv = 1.f/32768.f;
        float mean = s1[0]*inv, var = s2[0]*inv - mean*mean;
        float sc = gamma[c]*rsqrtf(var + 1e-5f);
        bn[512 + c] = sc; bn[768 + c] = fmaf(-mean, sc, beta[c]);
    }
}

// ---------------------------------------------------------------------------
// out = relu(h*s+b) + x ; grid=2048
// ---------------------------------------------------------------------------
__global__ __launch_bounds__(256) void k_apply(const unsigned short* __restrict__ h,
    const float* __restrict__ x, const float* __restrict__ bn, float* __restrict__ out)
{
    const size_t tot8 = (size_t)BB*CC*NN/8;
    for (size_t i = (size_t)blockIdx.x*256 + threadIdx.x; i < tot8; i += 2048*256){
        int c = (int)((i >> 10) & 255);
        float s = bn[512 + c], bb = bn[768 + c];
        short8v hv = *(const short8v*)(h + i*8);
        f32x4 x0 = *(const f32x4*)(x + i*8);
        f32x4 x1 = *(const f32x4*)(x + i*8 + 4);
        f32x4 o0, o1;
        #pragma unroll
        for (int j = 0; j < 4; ++j){
            o0[j] = fmaxf(fmaf(bu2f((unsigned short)hv[j]),     s, bb), 0.f) + x0[j];
            o1[j] = fmaxf(fmaf(bu2f((unsigned short)hv[4 + j]), s, bb), 0.f) + x1[j];
        }
        *(f32x4*)(out + i*8)     = o0;
        *(f32x4*)(out + i*8 + 4) = o1;
    }
}

extern "C" void kernel_launch(void* const* d_in, const int* in_sizes, int n_in,
                              void* d_out, int out_size, void* d_ws, size_t ws_size,
                              hipStream_t stream)
{
    (void)in_sizes; (void)n_in; (void)out_size; (void)ws_size;
    const float* x       = (const float*)d_in[0];
    const float* pos     = (const float*)d_in[1];
    const float* Wq      = (const float*)d_in[2];
    const float* Wk      = (const float*)d_in[3];
    const float* Wv      = (const float*)d_in[4];
    const float* Psm     = (const float*)d_in[5];
    const float* Wg1     = (const float*)d_in[6];
    const float* bg1     = (const float*)d_in[7];
    const float* Wg2     = (const float*)d_in[8];
    const float* bg2     = (const float*)d_in[9];
    const float* log_tau = (const float*)d_in[10];
    const float* omega   = (const float*)d_in[11];
    const float* Wp      = (const float*)d_in[12];
    const float* gamma   = (const float*)d_in[13];
    const float* beta    = (const float*)d_in[14];
    char* W = (char*)d_ws;
    float* out = (float*)d_out;

    unsigned short* qp    = (unsigned short*)(W + P_QP);
    unsigned short* kp_t  = (unsigned short*)(W + P_KPT);
    unsigned short* phir  = (unsigned short*)(W + P_PHIR);
    unsigned short* phit  = (unsigned short*)(W + P_PHIT);
    unsigned short* xT    = (unsigned short*)(W + P_XT);
    unsigned short* v_t   = (unsigned short*)(W + P_VT);
    unsigned short* y_nt  = (unsigned short*)(W + P_YNT);
    unsigned short* kv_t  = (unsigned short*)(W + P_KVT);
    float*          kvf   = (float*)(W + P_KVF);
    float*          ksum  = (float*)(W + P_KSUM);
    float*          den   = (float*)(W + P_DEN);
    unsigned short* Wqk_b = (unsigned short*)(W + P_WQK);
    unsigned short* Wv_b  = (unsigned short*)(W + P_WV);
    unsigned short* Wp_b  = (unsigned short*)(W + P_WP);
    unsigned short* Psm_t = (unsigned short*)(W + P_PSMT);
    float*          bn    = (float*)(W + P_BN);
    unsigned short* hbuf  = (unsigned short*)(W + P_H);

    hipMemsetAsync(W + P_KVF, 0, 8421376, stream);   // kv_f32 + ksum
    k_prep  <<<  64, 256, 0, stream>>>(Wq, Wk, Wv, Wp, Psm, Wqk_b, Wv_b, Wp_b, Psm_t);
    k_xt    <<<2048, 256, 0, stream>>>(x, xT);
    k_wgemm <<<2048, 256, 0, stream>>>(Wv_b, xT, v_t, 256);
    k_qk    <<< 512, 256, 0, stream>>>(Wqk_b, xT, Psm_t, qp, kp_t);
    k_phi   <<< 128, 256, 0, stream>>>(pos, Wg1, bg1, Wg2, bg2, log_tau, omega, phir, phit);
    k_kv    <<<1024, 256, 0, stream>>>(kp_t, phit, v_t, kvf, ksum);
    k_kvred <<<2048, 256, 0, stream>>>(kvf, kv_t);
    k_denom <<< 128, 256, 0, stream>>>(qp, phir, ksum, den);
    k_fsa   <<< 512, 256, 0, stream>>>(kv_t, qp, phir, den, xT, y_nt);
    k_wgemm <<<2048, 256, 0, stream>>>(Wp_b, y_nt, hbuf, 256);
    k_bnstat<<< 256, 256, 0, stream>>>(hbuf, gamma, beta, bn);
    k_apply <<<2048, 256, 0, stream>>>(hbuf, x, bn, out);
}